// Round 1
// baseline (996.839 us; speedup 1.0000x reference)
//
#include <hip/hip_runtime.h>

#define B_ 8
#define H_ 96
#define W_ 96
#define C_ 256
#define NH_ 8
#define D_ 32
#define M_ (B_*H_*W_)              // 73728 pixels
static const size_t SZf = (size_t)M_ * C_;   // elements per (B,H,W,C) buffer

// ---------------------------------------------------------------------------
// Kernel 1: fused QKV projections.
// q = x@Wq + bq ; k = (x@Wk + bk + enc) * d^-0.5 ; v = x@Wv + bv + enc
// BM=BN=128, BK=32, 256 threads, 8x8 microtile. grid (6, 576):
//   blockIdx.x: 0..5 -> which weight (x>>1) and col half ((x&1)*128)
// ---------------------------------------------------------------------------
__global__ __launch_bounds__(256) void qkv_gemm(
    const float* __restrict__ x, const float* __restrict__ enc,
    const float* __restrict__ Wq, const float* __restrict__ bq,
    const float* __restrict__ Wk, const float* __restrict__ bk,
    const float* __restrict__ Wv, const float* __restrict__ bv,
    float* __restrict__ q, float* __restrict__ k, float* __restrict__ v)
{
    __shared__ float sA[128][36];   // [m][k], padded
    __shared__ float sB[32][136];   // [k][n], padded (16B-aligned rows)

    const int t = threadIdx.x;
    const int which = blockIdx.x >> 1;
    const int colbase = (blockIdx.x & 1) * 128;
    const int m0 = blockIdx.y * 128;
    const float* __restrict__ W    = which == 0 ? Wq : (which == 1 ? Wk : Wv);
    const float* __restrict__ bias = which == 0 ? bq : (which == 1 ? bk : bv);

    const int tx = t & 15, ty = t >> 4;
    float acc[8][8];
#pragma unroll
    for (int i = 0; i < 8; ++i)
#pragma unroll
        for (int j = 0; j < 8; ++j) acc[i][j] = 0.f;

    for (int k0 = 0; k0 < 256; k0 += 32) {
        // A tile: 128 rows x 32 k = 1024 float4, 4 per thread
#pragma unroll
        for (int r = 0; r < 4; ++r) {
            int idx = r * 256 + t;
            int row = idx >> 3, kq = idx & 7;
            float4 a4 = *(const float4*)(x + (size_t)(m0 + row) * C_ + k0 + kq * 4);
            *(float4*)(&sA[row][kq * 4]) = a4;
        }
        // B tile: 32 k x 128 cols = 1024 float4, 4 per thread
#pragma unroll
        for (int r = 0; r < 4; ++r) {
            int idx = r * 256 + t;
            int kk = idx >> 5, cq = idx & 31;
            float4 b4 = *(const float4*)(W + (size_t)(k0 + kk) * C_ + colbase + cq * 4);
            *(float4*)(&sB[kk][cq * 4]) = b4;
        }
        __syncthreads();
#pragma unroll
        for (int kk = 0; kk < 32; ++kk) {
            float av[8], bw[8];
#pragma unroll
            for (int i = 0; i < 8; ++i) av[i] = sA[ty * 8 + i][kk];
#pragma unroll
            for (int j = 0; j < 8; ++j) bw[j] = sB[kk][tx * 8 + j];
#pragma unroll
            for (int i = 0; i < 8; ++i)
#pragma unroll
                for (int j = 0; j < 8; ++j) acc[i][j] = fmaf(av[i], bw[j], acc[i][j]);
        }
        __syncthreads();
    }

    const float scaling = 0.17677669529663687f;   // 32^-0.5
#pragma unroll
    for (int i = 0; i < 8; ++i) {
        int m = m0 + ty * 8 + i;
        size_t rowoff = (size_t)m * C_;
#pragma unroll
        for (int j = 0; j < 8; ++j) {
            int col = colbase + tx * 8 + j;
            float cval = acc[i][j] + bias[col];
            size_t off = rowoff + col;
            if (which == 0)      q[off] = cval;
            else if (which == 1) k[off] = (cval + enc[off]) * scaling;
            else                 v[off] = cval + enc[off];
        }
    }
}

// ---------------------------------------------------------------------------
// Kernel 2: depthwise 5x5 conv (stride 1, pad 2) + bias -> lepe.
// One thread per (pixel, 4 channels). grid = M_*64/256 blocks.
// ---------------------------------------------------------------------------
__global__ __launch_bounds__(256) void dwconv5x5(
    const float* __restrict__ v, const float* __restrict__ cw,
    const float* __restrict__ cb, float* __restrict__ lepe)
{
    size_t tid = (size_t)blockIdx.x * 256 + threadIdx.x;   // [0, M_*64)
    int c4 = (int)(tid & 63);
    size_t pix = tid >> 6;
    int w = (int)(pix % W_);
    size_t tmp = pix / W_;
    int h = (int)(tmp % H_);
    int b = (int)(tmp / H_);
    int c0 = c4 * 4;

    float4 acc = { cb[c0], cb[c0 + 1], cb[c0 + 2], cb[c0 + 3] };
#pragma unroll
    for (int dy = -2; dy <= 2; ++dy) {
        int hy = h + dy;
        if (hy < 0 || hy >= H_) continue;
#pragma unroll
        for (int dx = -2; dx <= 2; ++dx) {
            int wx = w + dx;
            if (wx < 0 || wx >= W_) continue;
            float4 vv = *(const float4*)(v + (((size_t)b * H_ + hy) * W_ + wx) * C_ + c0);
            float4 ww = *(const float4*)(cw + (size_t)((dy + 2) * 5 + (dx + 2)) * C_ + c0);
            acc.x += vv.x * ww.x; acc.y += vv.y * ww.y;
            acc.z += vv.z * ww.z; acc.w += vv.w * ww.w;
        }
    }
    *(float4*)(lepe + pix * C_ + c0) = acc;
}

// ---------------------------------------------------------------------------
// Kernel 3/4: axial attention with LOG-softmax, in-place over vio.
// Per block: one (b, o, n) slice of 96 positions x d=32.
//   width:  o = image row h,  ofac = W_,  pstride = C_
//   height: o = image col w,  ofac = 1,   pstride = W_*C_
// S = q k^T (k pre-scaled); A = S - logsumexp_row(S); vio <- A @ vio.
// ---------------------------------------------------------------------------
__global__ __launch_bounds__(256) void axial_attn(
    const float* __restrict__ q, const float* __restrict__ k,
    float* __restrict__ vio, int ofac, int pstride)
{
    __shared__ float sq[96][33];
    __shared__ float sk[96][33];
    __shared__ float sv[96][33];
    __shared__ float sS[96][97];

    const int t = threadIdx.x;
    const int n = blockIdx.x & 7;
    const int o = (blockIdx.x >> 3) % 96;
    const int b = blockIdx.x / (8 * 96);
    const size_t base = ((size_t)b * H_ * W_ + (size_t)o * ofac) * C_ + n * D_;

    // Load q,k,v tiles (96 x 32 each)
    for (int idx = t; idx < 96 * 8; idx += 256) {
        int row = idx >> 3, f = idx & 7;
        size_t g = base + (size_t)row * pstride + f * 4;
        float4 a = *(const float4*)(q + g);
        sq[row][f * 4 + 0] = a.x; sq[row][f * 4 + 1] = a.y;
        sq[row][f * 4 + 2] = a.z; sq[row][f * 4 + 3] = a.w;
        float4 bb = *(const float4*)(k + g);
        sk[row][f * 4 + 0] = bb.x; sk[row][f * 4 + 1] = bb.y;
        sk[row][f * 4 + 2] = bb.z; sk[row][f * 4 + 3] = bb.w;
        float4 c = *(const float4*)(vio + g);
        sv[row][f * 4 + 0] = c.x; sv[row][f * 4 + 1] = c.y;
        sv[row][f * 4 + 2] = c.z; sv[row][f * 4 + 3] = c.w;
    }
    __syncthreads();

    // Scores: 16x16 threads, 6x6 microtile each -> 96x96
    {
        const int tx = t & 15, ty = t >> 4;
        float acc[6][6];
#pragma unroll
        for (int i = 0; i < 6; ++i)
#pragma unroll
            for (int j = 0; j < 6; ++j) acc[i][j] = 0.f;
#pragma unroll
        for (int kk = 0; kk < 32; ++kk) {
            float a[6], bb[6];
#pragma unroll
            for (int i = 0; i < 6; ++i) a[i] = sq[ty * 6 + i][kk];
#pragma unroll
            for (int j = 0; j < 6; ++j) bb[j] = sk[tx * 6 + j][kk];
#pragma unroll
            for (int i = 0; i < 6; ++i)
#pragma unroll
                for (int j = 0; j < 6; ++j) acc[i][j] = fmaf(a[i], bb[j], acc[i][j]);
        }
#pragma unroll
        for (int i = 0; i < 6; ++i)
#pragma unroll
            for (int j = 0; j < 6; ++j) sS[ty * 6 + i][tx * 6 + j] = acc[i][j];
    }
    __syncthreads();

    // Row-wise LOG-softmax: A = S - (m + log(sum exp(S - m)))
    if (t < 96) {
        float m = -1e30f;
        for (int j = 0; j < 96; ++j) m = fmaxf(m, sS[t][j]);
        float l = 0.f;
        for (int j = 0; j < 96; ++j) l += __expf(sS[t][j] - m);
        float off = m + __logf(l);
        for (int j = 0; j < 96; ++j) sS[t][j] -= off;
    }
    __syncthreads();

    // PV: out(96x32) = A(96x96) @ sv(96x32); 16x16 threads, 6 rows x 2 cols each
    {
        const int tx = t & 15, ty = t >> 4;
        float acc[6][2];
#pragma unroll
        for (int i = 0; i < 6; ++i) { acc[i][0] = 0.f; acc[i][1] = 0.f; }
        for (int j = 0; j < 96; ++j) {
            float v0 = sv[j][tx * 2 + 0];
            float v1 = sv[j][tx * 2 + 1];
#pragma unroll
            for (int i = 0; i < 6; ++i) {
                float a = sS[ty * 6 + i][j];
                acc[i][0] = fmaf(a, v0, acc[i][0]);
                acc[i][1] = fmaf(a, v1, acc[i][1]);
            }
        }
#pragma unroll
        for (int i = 0; i < 6; ++i) {
            int row = ty * 6 + i;
            size_t g = base + (size_t)row * pstride + tx * 2;
            float2 r2 = make_float2(acc[i][0], acc[i][1]);
            *(float2*)(vio + g) = r2;
        }
    }
}

// ---------------------------------------------------------------------------
// Kernel 5: out = (attn + lepe) @ Wo + bo.  Same tiling as qkv_gemm, N=256.
// grid (2, 576).
// ---------------------------------------------------------------------------
__global__ __launch_bounds__(256) void out_gemm(
    const float* __restrict__ a0, const float* __restrict__ a1,
    const float* __restrict__ Wo, const float* __restrict__ bo,
    float* __restrict__ out)
{
    __shared__ float sA[128][36];
    __shared__ float sB[32][136];

    const int t = threadIdx.x;
    const int colbase = blockIdx.x * 128;
    const int m0 = blockIdx.y * 128;
    const int tx = t & 15, ty = t >> 4;

    float acc[8][8];
#pragma unroll
    for (int i = 0; i < 8; ++i)
#pragma unroll
        for (int j = 0; j < 8; ++j) acc[i][j] = 0.f;

    for (int k0 = 0; k0 < 256; k0 += 32) {
#pragma unroll
        for (int r = 0; r < 4; ++r) {
            int idx = r * 256 + t;
            int row = idx >> 3, kq = idx & 7;
            size_t g = (size_t)(m0 + row) * C_ + k0 + kq * 4;
            float4 a4 = *(const float4*)(a0 + g);
            float4 b4 = *(const float4*)(a1 + g);
            a4.x += b4.x; a4.y += b4.y; a4.z += b4.z; a4.w += b4.w;
            *(float4*)(&sA[row][kq * 4]) = a4;
        }
#pragma unroll
        for (int r = 0; r < 4; ++r) {
            int idx = r * 256 + t;
            int kk = idx >> 5, cq = idx & 31;
            float4 b4 = *(const float4*)(Wo + (size_t)(k0 + kk) * C_ + colbase + cq * 4);
            *(float4*)(&sB[kk][cq * 4]) = b4;
        }
        __syncthreads();
#pragma unroll
        for (int kk = 0; kk < 32; ++kk) {
            float av[8], bw[8];
#pragma unroll
            for (int i = 0; i < 8; ++i) av[i] = sA[ty * 8 + i][kk];
#pragma unroll
            for (int j = 0; j < 8; ++j) bw[j] = sB[kk][tx * 8 + j];
#pragma unroll
            for (int i = 0; i < 8; ++i)
#pragma unroll
                for (int j = 0; j < 8; ++j) acc[i][j] = fmaf(av[i], bw[j], acc[i][j]);
        }
        __syncthreads();
    }
#pragma unroll
    for (int i = 0; i < 8; ++i) {
        int m = m0 + ty * 8 + i;
        size_t rowoff = (size_t)m * C_;
#pragma unroll
        for (int j = 0; j < 8; ++j) {
            int col = colbase + tx * 8 + j;
            out[rowoff + col] = acc[i][j] + bo[col];
        }
    }
}

// d2d copy (fallback path when ws can't hold lepe)
__global__ __launch_bounds__(256) void copy_f4(
    const float4* __restrict__ src, float4* __restrict__ dst, size_t n4)
{
    size_t i = (size_t)blockIdx.x * 256 + threadIdx.x;
    size_t stride = (size_t)gridDim.x * 256;
    for (; i < n4; i += stride) dst[i] = src[i];
}

extern "C" void kernel_launch(void* const* d_in, const int* in_sizes, int n_in,
                              void* d_out, int out_size, void* d_ws, size_t ws_size,
                              hipStream_t stream)
{
    const float* x   = (const float*)d_in[0];
    const float* enc = (const float*)d_in[1];
    const float* Wq  = (const float*)d_in[2];
    const float* bq  = (const float*)d_in[3];
    const float* Wk  = (const float*)d_in[4];
    const float* bk  = (const float*)d_in[5];
    const float* Wv  = (const float*)d_in[6];
    const float* bv  = (const float*)d_in[7];
    const float* cw  = (const float*)d_in[8];
    const float* cb  = (const float*)d_in[9];
    const float* Wo  = (const float*)d_in[10];
    const float* bo  = (const float*)d_in[11];
    float* out = (float*)d_out;
    float* ws  = (float*)d_ws;

    float* q = ws;
    float* k = ws + SZf;
    float* v = ws + 2 * SZf;           // becomes v1 after width attn, out2 after height attn
    bool ws_fits = ws_size >= 4 * SZf * sizeof(float);
    float* lepe = ws_fits ? (ws + 3 * SZf) : out;

    // 1) projections
    qkv_gemm<<<dim3(6, 576), 256, 0, stream>>>(x, enc, Wq, bq, Wk, bk, Wv, bv, q, k, v);
    // 2) LePE depthwise conv (reads v before it is overwritten)
    dwconv5x5<<<(M_ * 64) / 256, 256, 0, stream>>>(v, cw, cb, lepe);
    // 3) width axial attention (o = row h), in place over v
    axial_attn<<<B_ * H_ * NH_, 256, 0, stream>>>(q, k, v, W_, C_);
    // 4) height axial attention (o = col w), in place over v
    axial_attn<<<B_ * W_ * NH_, 256, 0, stream>>>(q, k, v, 1, W_ * C_);
    // 5) output projection; if lepe lives in d_out, move it to the (now free) q buffer
    const float* lep_src = lepe;
    if (!ws_fits) {
        copy_f4<<<2048, 256, 0, stream>>>((const float4*)out, (float4*)q, SZf / 4);
        lep_src = q;
    }
    out_gemm<<<dim3(2, 576), 256, 0, stream>>>(v, lep_src, Wo, bo, out);
}

// Round 2
// 775.490 us; speedup vs baseline: 1.2854x; 1.2854x over previous
//
#include <hip/hip_runtime.h>

#define B_ 8
#define H_ 96
#define W_ 96
#define C_ 256
#define NH_ 8
#define D_ 32
#define M_ (B_*H_*W_)              // 73728 pixels
static const size_t SZf = (size_t)M_ * C_;   // elements per (B,H,W,C) buffer

typedef unsigned short u16;
typedef short bf16x8 __attribute__((ext_vector_type(8)));   // 8 bf16 = 4 VGPRs
typedef float f32x4 __attribute__((ext_vector_type(4)));

__device__ __forceinline__ u16 f2b(float f) {                // fp32 -> bf16 RNE
    unsigned u = __float_as_uint(f);
    return (u16)((u + 0x7FFFu + ((u >> 16) & 1u)) >> 16);
}
__device__ __forceinline__ float b2f(u16 h) {
    return __uint_as_float(((unsigned)h) << 16);
}

// ---------------------------------------------------------------------------
// prep_x: x (fp32) -> xb (bf16). grid 9216 x 256, 8 elements/thread.
// ---------------------------------------------------------------------------
__global__ __launch_bounds__(256) void prep_x(
    const float* __restrict__ x, u16* __restrict__ xb)
{
    size_t base = ((size_t)blockIdx.x * 256 + threadIdx.x) * 8;
    float4 a = *(const float4*)(x + base);
    float4 b = *(const float4*)(x + base + 4);
    ushort4 o0 = make_ushort4(f2b(a.x), f2b(a.y), f2b(a.z), f2b(a.w));
    ushort4 o1 = make_ushort4(f2b(b.x), f2b(b.y), f2b(b.z), f2b(b.w));
    *(ushort4*)(xb + base) = o0;
    *(ushort4*)(xb + base + 4) = o1;
}

// ---------------------------------------------------------------------------
// prep_w: W[k][n] fp32 -> WT[w][n][k] bf16 (transposed, n-major) for q,k,v,o.
// grid 1024 x 256 (each weight is 65536 elements; blocks never straddle w).
// ---------------------------------------------------------------------------
__global__ __launch_bounds__(256) void prep_w(
    const float* __restrict__ Wq, const float* __restrict__ Wk,
    const float* __restrict__ Wv, const float* __restrict__ Wo,
    u16* __restrict__ WT)
{
    int id = blockIdx.x * 256 + threadIdx.x;
    int w = id >> 16;
    int r = id & 65535;
    int n = r >> 8;
    int kk = r & 255;
    const float* Wp = (w == 0) ? Wq : (w == 1) ? Wk : (w == 2) ? Wv : Wo;
    WT[(size_t)id] = f2b(Wp[(size_t)kk * 256 + n]);
}

// ---------------------------------------------------------------------------
// qkv_mfma: q = xb@Wq + bq ; k = (xb@Wk + bk + enc)*d^-0.5 ; v = xb@Wv + bv + enc
// MFMA 16x16x32 bf16, fp32 accumulate. 128x128 tile, BK=64, 256 thr = 4 waves
// (2x2), each wave 64x64 = 4x4 fragments. LDS [128][72] bf16: 144B row stride
// (16B aligned, bank step 4 -> conflict-free b128 reads/writes).
// grid (6, 576): x>>1 = which weight, (x&1)*128 = col half.
// ---------------------------------------------------------------------------
__global__ __launch_bounds__(256, 2) void qkv_mfma(
    const u16* __restrict__ xb, const float* __restrict__ enc,
    const u16* __restrict__ WT,
    const float* __restrict__ bq, const float* __restrict__ bk,
    const float* __restrict__ bv,
    float* __restrict__ q, float* __restrict__ k, float* __restrict__ v)
{
    __shared__ u16 sA[128][72];
    __shared__ u16 sB[128][72];

    const int t = threadIdx.x;
    const int which = blockIdx.x >> 1;
    const int colbase = (blockIdx.x & 1) * 128;
    const int m0 = blockIdx.y * 128;
    const u16* __restrict__ Wt = WT + (size_t)which * 65536;

    const int wave = t >> 6, lane = t & 63;
    const int wr = wave >> 1, wc = wave & 1;
    const int l16 = lane & 15, kg = lane >> 4;
    const int ra = t >> 1, ha = t & 1;

    f32x4 acc[4][4];
#pragma unroll
    for (int i = 0; i < 4; ++i)
#pragma unroll
        for (int j = 0; j < 4; ++j) acc[i][j] = (f32x4){0.f, 0.f, 0.f, 0.f};

    for (int k0 = 0; k0 < 256; k0 += 64) {
        const u16* gA = xb + (size_t)(m0 + ra) * 256 + k0 + ha * 32;
        const u16* gB = Wt + (size_t)(colbase + ra) * 256 + k0 + ha * 32;
#pragma unroll
        for (int i = 0; i < 4; ++i) {
            *(float4*)(&sA[ra][ha * 32 + i * 8]) = *(const float4*)(gA + i * 8);
            *(float4*)(&sB[ra][ha * 32 + i * 8]) = *(const float4*)(gB + i * 8);
        }
        __syncthreads();
#pragma unroll
        for (int ks = 0; ks < 2; ++ks) {
            bf16x8 af[4], bf[4];
#pragma unroll
            for (int mi = 0; mi < 4; ++mi)
                af[mi] = *(const bf16x8*)(&sA[wr * 64 + mi * 16 + l16][ks * 32 + kg * 8]);
#pragma unroll
            for (int ni = 0; ni < 4; ++ni)
                bf[ni] = *(const bf16x8*)(&sB[wc * 64 + ni * 16 + l16][ks * 32 + kg * 8]);
#pragma unroll
            for (int mi = 0; mi < 4; ++mi)
#pragma unroll
                for (int ni = 0; ni < 4; ++ni)
                    acc[mi][ni] = __builtin_amdgcn_mfma_f32_16x16x32_bf16(
                        af[mi], bf[ni], acc[mi][ni], 0, 0, 0);
        }
        __syncthreads();
    }

    // epilogue: C/D layout col = lane&15, row = (lane>>4)*4 + reg
    const float scaling = 0.17677669529663687f;
    const float* __restrict__ bias = (which == 0) ? bq : (which == 1) ? bk : bv;
#pragma unroll
    for (int mi = 0; mi < 4; ++mi) {
#pragma unroll
        for (int ni = 0; ni < 4; ++ni) {
            int col = colbase + wc * 64 + ni * 16 + l16;
            float bv_ = bias[col];
#pragma unroll
            for (int r = 0; r < 4; ++r) {
                int row = m0 + wr * 64 + mi * 16 + kg * 4 + r;
                size_t off = (size_t)row * 256 + col;
                float cv = acc[mi][ni][r] + bv_;
                if (which == 0)      q[off] = cv;
                else if (which == 1) k[off] = (cv + enc[off]) * scaling;
                else                 v[off] = cv + enc[off];
            }
        }
    }
}

// ---------------------------------------------------------------------------
// dwconv5x5: depthwise 5x5 + bias -> lepe (bf16). One thread per (pixel, 4ch).
// ---------------------------------------------------------------------------
__global__ __launch_bounds__(256) void dwconv5x5(
    const float* __restrict__ v, const float* __restrict__ cw,
    const float* __restrict__ cb, u16* __restrict__ lepe)
{
    size_t tid = (size_t)blockIdx.x * 256 + threadIdx.x;
    int c4 = (int)(tid & 63);
    size_t pix = tid >> 6;
    int w = (int)(pix % W_);
    size_t tmp = pix / W_;
    int h = (int)(tmp % H_);
    int b = (int)(tmp / H_);
    int c0 = c4 * 4;

    float4 acc = { cb[c0], cb[c0 + 1], cb[c0 + 2], cb[c0 + 3] };
#pragma unroll
    for (int dy = -2; dy <= 2; ++dy) {
        int hy = h + dy;
        if (hy < 0 || hy >= H_) continue;
#pragma unroll
        for (int dx = -2; dx <= 2; ++dx) {
            int wx = w + dx;
            if (wx < 0 || wx >= W_) continue;
            float4 vv = *(const float4*)(v + (((size_t)b * H_ + hy) * W_ + wx) * C_ + c0);
            float4 ww = *(const float4*)(cw + (size_t)((dy + 2) * 5 + (dx + 2)) * C_ + c0);
            acc.x += vv.x * ww.x; acc.y += vv.y * ww.y;
            acc.z += vv.z * ww.z; acc.w += vv.w * ww.w;
        }
    }
    ushort4 o = make_ushort4(f2b(acc.x), f2b(acc.y), f2b(acc.z), f2b(acc.w));
    *(ushort4*)(lepe + pix * C_ + c0) = o;
}

// ---------------------------------------------------------------------------
// axial_attn: LOG-softmax axial attention, in place over vio (fp32, unchanged).
// ---------------------------------------------------------------------------
__global__ __launch_bounds__(256) void axial_attn(
    const float* __restrict__ q, const float* __restrict__ k,
    float* __restrict__ vio, int ofac, int pstride)
{
    __shared__ float sq[96][33];
    __shared__ float sk[96][33];
    __shared__ float sv[96][33];
    __shared__ float sS[96][97];

    const int t = threadIdx.x;
    const int n = blockIdx.x & 7;
    const int o = (blockIdx.x >> 3) % 96;
    const int b = blockIdx.x / (8 * 96);
    const size_t base = ((size_t)b * H_ * W_ + (size_t)o * ofac) * C_ + n * D_;

    for (int idx = t; idx < 96 * 8; idx += 256) {
        int row = idx >> 3, f = idx & 7;
        size_t g = base + (size_t)row * pstride + f * 4;
        float4 a = *(const float4*)(q + g);
        sq[row][f * 4 + 0] = a.x; sq[row][f * 4 + 1] = a.y;
        sq[row][f * 4 + 2] = a.z; sq[row][f * 4 + 3] = a.w;
        float4 bb = *(const float4*)(k + g);
        sk[row][f * 4 + 0] = bb.x; sk[row][f * 4 + 1] = bb.y;
        sk[row][f * 4 + 2] = bb.z; sk[row][f * 4 + 3] = bb.w;
        float4 c = *(const float4*)(vio + g);
        sv[row][f * 4 + 0] = c.x; sv[row][f * 4 + 1] = c.y;
        sv[row][f * 4 + 2] = c.z; sv[row][f * 4 + 3] = c.w;
    }
    __syncthreads();

    {
        const int tx = t & 15, ty = t >> 4;
        float acc[6][6];
#pragma unroll
        for (int i = 0; i < 6; ++i)
#pragma unroll
            for (int j = 0; j < 6; ++j) acc[i][j] = 0.f;
#pragma unroll
        for (int kk = 0; kk < 32; ++kk) {
            float a[6], bb[6];
#pragma unroll
            for (int i = 0; i < 6; ++i) a[i] = sq[ty * 6 + i][kk];
#pragma unroll
            for (int j = 0; j < 6; ++j) bb[j] = sk[tx * 6 + j][kk];
#pragma unroll
            for (int i = 0; i < 6; ++i)
#pragma unroll
                for (int j = 0; j < 6; ++j) acc[i][j] = fmaf(a[i], bb[j], acc[i][j]);
        }
#pragma unroll
        for (int i = 0; i < 6; ++i)
#pragma unroll
            for (int j = 0; j < 6; ++j) sS[ty * 6 + i][tx * 6 + j] = acc[i][j];
    }
    __syncthreads();

    if (t < 96) {
        float m = -1e30f;
        for (int j = 0; j < 96; ++j) m = fmaxf(m, sS[t][j]);
        float l = 0.f;
        for (int j = 0; j < 96; ++j) l += __expf(sS[t][j] - m);
        float off = m + __logf(l);
        for (int j = 0; j < 96; ++j) sS[t][j] -= off;
    }
    __syncthreads();

    {
        const int tx = t & 15, ty = t >> 4;
        float acc[6][2];
#pragma unroll
        for (int i = 0; i < 6; ++i) { acc[i][0] = 0.f; acc[i][1] = 0.f; }
        for (int j = 0; j < 96; ++j) {
            float v0 = sv[j][tx * 2 + 0];
            float v1 = sv[j][tx * 2 + 1];
#pragma unroll
            for (int i = 0; i < 6; ++i) {
                float a = sS[ty * 6 + i][j];
                acc[i][0] = fmaf(a, v0, acc[i][0]);
                acc[i][1] = fmaf(a, v1, acc[i][1]);
            }
        }
#pragma unroll
        for (int i = 0; i < 6; ++i) {
            int row = ty * 6 + i;
            size_t g = base + (size_t)row * pstride + tx * 2;
            float2 r2 = make_float2(acc[i][0], acc[i][1]);
            *(float2*)(vio + g) = r2;
        }
    }
}

// ---------------------------------------------------------------------------
// out_mfma: out = (attn + lepe) @ Wo + bo. A staged with fused fp32+bf16 add ->
// bf16 conversion; B = WoT bf16. Same MFMA tiling. grid (2, 576).
// ---------------------------------------------------------------------------
__global__ __launch_bounds__(256, 2) void out_mfma(
    const float* __restrict__ attn, const u16* __restrict__ lepeb,
    const u16* __restrict__ WoT, const float* __restrict__ bo,
    float* __restrict__ out)
{
    __shared__ u16 sA[128][72];
    __shared__ u16 sB[128][72];

    const int t = threadIdx.x;
    const int colbase = blockIdx.x * 128;
    const int m0 = blockIdx.y * 128;

    const int wave = t >> 6, lane = t & 63;
    const int wr = wave >> 1, wc = wave & 1;
    const int l16 = lane & 15, kg = lane >> 4;
    const int ra = t >> 1, ha = t & 1;

    f32x4 acc[4][4];
#pragma unroll
    for (int i = 0; i < 4; ++i)
#pragma unroll
        for (int j = 0; j < 4; ++j) acc[i][j] = (f32x4){0.f, 0.f, 0.f, 0.f};

    for (int k0 = 0; k0 < 256; k0 += 64) {
        const float* gA = attn + (size_t)(m0 + ra) * 256 + k0 + ha * 32;
        const u16* gL = lepeb + (size_t)(m0 + ra) * 256 + k0 + ha * 32;
        const u16* gB = WoT + (size_t)(colbase + ra) * 256 + k0 + ha * 32;
#pragma unroll
        for (int i = 0; i < 4; ++i) {
            float4 f0 = *(const float4*)(gA + i * 8);
            float4 f1 = *(const float4*)(gA + i * 8 + 4);
            ushort4 l0 = *(const ushort4*)(gL + i * 8);
            ushort4 l1 = *(const ushort4*)(gL + i * 8 + 4);
            ushort4 o0 = make_ushort4(f2b(f0.x + b2f(l0.x)), f2b(f0.y + b2f(l0.y)),
                                      f2b(f0.z + b2f(l0.z)), f2b(f0.w + b2f(l0.w)));
            ushort4 o1 = make_ushort4(f2b(f1.x + b2f(l1.x)), f2b(f1.y + b2f(l1.y)),
                                      f2b(f1.z + b2f(l1.z)), f2b(f1.w + b2f(l1.w)));
            *(ushort4*)(&sA[ra][ha * 32 + i * 8]) = o0;
            *(ushort4*)(&sA[ra][ha * 32 + i * 8 + 4]) = o1;
            *(float4*)(&sB[ra][ha * 32 + i * 8]) = *(const float4*)(gB + i * 8);
        }
        __syncthreads();
#pragma unroll
        for (int ks = 0; ks < 2; ++ks) {
            bf16x8 af[4], bf[4];
#pragma unroll
            for (int mi = 0; mi < 4; ++mi)
                af[mi] = *(const bf16x8*)(&sA[wr * 64 + mi * 16 + l16][ks * 32 + kg * 8]);
#pragma unroll
            for (int ni = 0; ni < 4; ++ni)
                bf[ni] = *(const bf16x8*)(&sB[wc * 64 + ni * 16 + l16][ks * 32 + kg * 8]);
#pragma unroll
            for (int mi = 0; mi < 4; ++mi)
#pragma unroll
                for (int ni = 0; ni < 4; ++ni)
                    acc[mi][ni] = __builtin_amdgcn_mfma_f32_16x16x32_bf16(
                        af[mi], bf[ni], acc[mi][ni], 0, 0, 0);
        }
        __syncthreads();
    }

#pragma unroll
    for (int mi = 0; mi < 4; ++mi) {
#pragma unroll
        for (int ni = 0; ni < 4; ++ni) {
            int col = colbase + wc * 64 + ni * 16 + l16;
            float bv_ = bo[col];
#pragma unroll
            for (int r = 0; r < 4; ++r) {
                int row = m0 + wr * 64 + mi * 16 + kg * 4 + r;
                out[(size_t)row * 256 + col] = acc[mi][ni][r] + bv_;
            }
        }
    }
}

__global__ __launch_bounds__(256) void copy_f4(
    const float4* __restrict__ src, float4* __restrict__ dst, size_t n4)
{
    size_t i = (size_t)blockIdx.x * 256 + threadIdx.x;
    size_t stride = (size_t)gridDim.x * 256;
    for (; i < n4; i += stride) dst[i] = src[i];
}

extern "C" void kernel_launch(void* const* d_in, const int* in_sizes, int n_in,
                              void* d_out, int out_size, void* d_ws, size_t ws_size,
                              hipStream_t stream)
{
    const float* x   = (const float*)d_in[0];
    const float* enc = (const float*)d_in[1];
    const float* Wq  = (const float*)d_in[2];
    const float* bq  = (const float*)d_in[3];
    const float* Wk  = (const float*)d_in[4];
    const float* bk  = (const float*)d_in[5];
    const float* Wv  = (const float*)d_in[6];
    const float* bv  = (const float*)d_in[7];
    const float* cw  = (const float*)d_in[8];
    const float* cb  = (const float*)d_in[9];
    const float* Wo  = (const float*)d_in[10];
    const float* bo  = (const float*)d_in[11];
    float* out = (float*)d_out;
    float* ws  = (float*)d_ws;

    float* q = ws;
    float* k = ws + SZf;
    float* v = ws + 2 * SZf;
    u16*   WT = (u16*)(ws + 3 * SZf);               // 4 x 65536 bf16 = 512 KB

    // plan A: xb + lepe(bf16) also in ws (needs (4*SZf + 131072) * 4 bytes)
    bool planA = ws_size >= (4 * SZf + 131072) * sizeof(float);
    u16* xb    = planA ? (u16*)(ws + 3 * SZf + 131072) : (u16*)d_out;
    u16* lepeb = xb + SZf;

    prep_x<<<(int)(SZf / 8 / 256), 256, 0, stream>>>(x, xb);
    prep_w<<<1024, 256, 0, stream>>>(Wq, Wk, Wv, Wo, WT);
    qkv_mfma<<<dim3(6, 576), 256, 0, stream>>>(xb, enc, WT, bq, bk, bv, q, k, v);
    dwconv5x5<<<(M_ * 64) / 256, 256, 0, stream>>>(v, cw, cb, lepeb);
    axial_attn<<<B_ * H_ * NH_, 256, 0, stream>>>(q, k, v, W_, C_);
    axial_attn<<<B_ * W_ * NH_, 256, 0, stream>>>(q, k, v, 1, W_ * C_);

    const u16* lep_src = lepeb;
    if (!planA) {
        // lepe lives in d_out's upper half; move to (free) q buffer before out
        copy_f4<<<2048, 256, 0, stream>>>((const float4*)lepeb, (float4*)q, SZf / 8);
        lep_src = (const u16*)q;
    }
    out_mfma<<<dim3(2, 576), 256, 0, stream>>>(v, lep_src, WT + 3 * 65536, bo, out);
}

// Round 3
// 354.288 us; speedup vs baseline: 2.8136x; 2.1889x over previous
//
#include <hip/hip_runtime.h>

#define B_ 8
#define S_ 96
#define C_ 256
#define NH_ 8
#define D_ 32
#define M_ (B_*S_*S_)
static const size_t SZ = (size_t)M_ * C_;

typedef unsigned short u16;
typedef short bf16x8 __attribute__((ext_vector_type(8)));
typedef float f32x4 __attribute__((ext_vector_type(4)));

__device__ __forceinline__ u16 f2b(float f) {                // fp32 -> bf16 RNE
    unsigned u = __float_as_uint(f);
    return (u16)((u + 0x7FFFu + ((u >> 16) & 1u)) >> 16);
}
__device__ __forceinline__ float b2f(u16 h) { return __uint_as_float(((unsigned)h) << 16); }

__device__ __forceinline__ void gload16(const u16* g, u16* l) {
    __builtin_amdgcn_global_load_lds(
        (const __attribute__((address_space(1))) u16*)g,
        (__attribute__((address_space(3))) u16*)l, 16, 0, 0);
}

// ---------------------------------------------------------------------------
// prep_x: x fp32 -> xb bf16 (8 elems/thread)
// ---------------------------------------------------------------------------
__global__ __launch_bounds__(256) void prep_x(
    const float* __restrict__ x, u16* __restrict__ xb)
{
    size_t base = ((size_t)blockIdx.x * 256 + threadIdx.x) * 8;
    float4 a = *(const float4*)(x + base);
    float4 b = *(const float4*)(x + base + 4);
    u16 o[8] = { f2b(a.x), f2b(a.y), f2b(a.z), f2b(a.w),
                 f2b(b.x), f2b(b.y), f2b(b.z), f2b(b.w) };
    *(int4*)(xb + base) = *(int4*)o;
}

// ---------------------------------------------------------------------------
// prep_w: W[k][n] fp32 -> WT[w][n][k] bf16 for q,k,v,o
// ---------------------------------------------------------------------------
__global__ __launch_bounds__(256) void prep_w(
    const float* __restrict__ Wq, const float* __restrict__ Wk,
    const float* __restrict__ Wv, const float* __restrict__ Wo,
    u16* __restrict__ WT)
{
    int id = blockIdx.x * 256 + threadIdx.x;
    int w = id >> 16;
    int r = id & 65535;
    int n = r >> 8;
    int kk = r & 255;
    const float* Wp = (w == 0) ? Wq : (w == 1) ? Wk : (w == 2) ? Wv : Wo;
    WT[(size_t)id] = f2b(Wp[(size_t)kk * 256 + n]);
}

// ---------------------------------------------------------------------------
// proj_q: q = bf16(xb @ Wq + bq). 128x128 tile, BK=64, global_load_lds w16,
// XOR-swizzled source (slot' = slot ^ (row&7)), linear LDS [128][64].
// ---------------------------------------------------------------------------
#define STAGE4(gbase, lds, k0)                                                  \
    _Pragma("unroll")                                                           \
    for (int i = 0; i < 4; ++i) {                                               \
        int row8 = wave * 32 + i * 8;                                           \
        gload16((gbase) + (size_t)(row8 + lrow) * C_ + (k0) + sslot * 8,        \
                (lds) + row8 * 64);                                             \
    }

__global__ __launch_bounds__(256, 3) void proj_q(
    const u16* __restrict__ xb, const u16* __restrict__ WT,
    const float* __restrict__ bq, u16* __restrict__ q)
{
    __shared__ u16 sA[128 * 64];
    __shared__ u16 sB[128 * 64];
    const int t = threadIdx.x;
    const int colbase = blockIdx.x * 128;
    const int m0 = blockIdx.y * 128;
    const int wave = t >> 6, lane = t & 63;
    const int wr = wave >> 1, wc = wave & 1;
    const int l16 = lane & 15, kg = lane >> 4;
    const int lrow = lane >> 3;
    const int sslot = (lane & 7) ^ lrow;

    const u16* gA = xb + (size_t)m0 * C_;
    const u16* gB = WT + (size_t)colbase * C_;

    f32x4 acc[4][4];
#pragma unroll
    for (int i = 0; i < 4; ++i)
#pragma unroll
        for (int j = 0; j < 4; ++j) acc[i][j] = (f32x4){0.f, 0.f, 0.f, 0.f};

    STAGE4(gA, sA, 0); STAGE4(gB, sB, 0);
    for (int k0 = 0; k0 < 256; k0 += 64) {
        __syncthreads();
#pragma unroll
        for (int ks = 0; ks < 2; ++ks) {
            bf16x8 af[4], bf[4];
#pragma unroll
            for (int mi = 0; mi < 4; ++mi) {
                int row = wr * 64 + mi * 16 + l16;
                int sl = (ks * 4 + kg) ^ (l16 & 7);
                af[mi] = *(const bf16x8*)(sA + row * 64 + sl * 8);
            }
#pragma unroll
            for (int ni = 0; ni < 4; ++ni) {
                int row = wc * 64 + ni * 16 + l16;
                int sl = (ks * 4 + kg) ^ (l16 & 7);
                bf[ni] = *(const bf16x8*)(sB + row * 64 + sl * 8);
            }
#pragma unroll
            for (int mi = 0; mi < 4; ++mi)
#pragma unroll
                for (int ni = 0; ni < 4; ++ni)
                    acc[mi][ni] = __builtin_amdgcn_mfma_f32_16x16x32_bf16(
                        af[mi], bf[ni], acc[mi][ni], 0, 0, 0);
        }
        __syncthreads();
        if (k0 < 192) { STAGE4(gA, sA, k0 + 64); STAGE4(gB, sB, k0 + 64); }
    }

#pragma unroll
    for (int mi = 0; mi < 4; ++mi)
#pragma unroll
        for (int ni = 0; ni < 4; ++ni) {
            int col = colbase + wc * 64 + ni * 16 + l16;
            float bqv = bq[col];
#pragma unroll
            for (int r = 0; r < 4; ++r) {
                int row = m0 + wr * 64 + mi * 16 + kg * 4 + r;
                q[(size_t)row * 256 + col] = f2b(acc[mi][ni][r] + bqv);
            }
        }
}

// ---------------------------------------------------------------------------
// proj_kv: k = bf16((xb@Wk + bk + enc)*scale); v = bf16(xb@Wv + bv + enc).
// enc read ONCE. Same staging as proj_q, two B tiles.
// ---------------------------------------------------------------------------
__global__ __launch_bounds__(256, 2) void proj_kv(
    const u16* __restrict__ xb, const float* __restrict__ enc,
    const u16* __restrict__ WT,
    const float* __restrict__ bk, const float* __restrict__ bv,
    u16* __restrict__ k, u16* __restrict__ v)
{
    __shared__ u16 sA[128 * 64];
    __shared__ u16 sB0[128 * 64];
    __shared__ u16 sB1[128 * 64];
    const int t = threadIdx.x;
    const int colbase = blockIdx.x * 128;
    const int m0 = blockIdx.y * 128;
    const int wave = t >> 6, lane = t & 63;
    const int wr = wave >> 1, wc = wave & 1;
    const int l16 = lane & 15, kg = lane >> 4;
    const int lrow = lane >> 3;
    const int sslot = (lane & 7) ^ lrow;

    const u16* gA = xb + (size_t)m0 * C_;
    const u16* gB0 = WT + 65536 + (size_t)colbase * C_;          // Wk^T
    const u16* gB1 = WT + 2 * 65536 + (size_t)colbase * C_;      // Wv^T

    f32x4 acck[4][4], accv[4][4];
#pragma unroll
    for (int i = 0; i < 4; ++i)
#pragma unroll
        for (int j = 0; j < 4; ++j) {
            acck[i][j] = (f32x4){0.f, 0.f, 0.f, 0.f};
            accv[i][j] = (f32x4){0.f, 0.f, 0.f, 0.f};
        }

    STAGE4(gA, sA, 0); STAGE4(gB0, sB0, 0); STAGE4(gB1, sB1, 0);
    for (int k0 = 0; k0 < 256; k0 += 64) {
        __syncthreads();
#pragma unroll
        for (int ks = 0; ks < 2; ++ks) {
            bf16x8 af[4], b0[4], b1[4];
#pragma unroll
            for (int mi = 0; mi < 4; ++mi) {
                int row = wr * 64 + mi * 16 + l16;
                int sl = (ks * 4 + kg) ^ (l16 & 7);
                af[mi] = *(const bf16x8*)(sA + row * 64 + sl * 8);
            }
#pragma unroll
            for (int ni = 0; ni < 4; ++ni) {
                int row = wc * 64 + ni * 16 + l16;
                int sl = (ks * 4 + kg) ^ (l16 & 7);
                b0[ni] = *(const bf16x8*)(sB0 + row * 64 + sl * 8);
                b1[ni] = *(const bf16x8*)(sB1 + row * 64 + sl * 8);
            }
#pragma unroll
            for (int mi = 0; mi < 4; ++mi)
#pragma unroll
                for (int ni = 0; ni < 4; ++ni) {
                    acck[mi][ni] = __builtin_amdgcn_mfma_f32_16x16x32_bf16(
                        af[mi], b0[ni], acck[mi][ni], 0, 0, 0);
                    accv[mi][ni] = __builtin_amdgcn_mfma_f32_16x16x32_bf16(
                        af[mi], b1[ni], accv[mi][ni], 0, 0, 0);
                }
        }
        __syncthreads();
        if (k0 < 192) { STAGE4(gA, sA, k0 + 64); STAGE4(gB0, sB0, k0 + 64); STAGE4(gB1, sB1, k0 + 64); }
    }

    const float SCALE = 0.17677669529663687f;
#pragma unroll
    for (int mi = 0; mi < 4; ++mi)
#pragma unroll
        for (int ni = 0; ni < 4; ++ni) {
            int col = colbase + wc * 64 + ni * 16 + l16;
            float bkv = bk[col], bvv = bv[col];
#pragma unroll
            for (int r = 0; r < 4; ++r) {
                int row = m0 + wr * 64 + mi * 16 + kg * 4 + r;
                size_t off = (size_t)row * 256 + col;
                float e = enc[off];
                k[off] = f2b((acck[mi][ni][r] + bkv + e) * SCALE);
                v[off] = f2b(accv[mi][ni][r] + bvv + e);
            }
        }
}

// ---------------------------------------------------------------------------
// dwconv5x5: v (bf16) -> lepe (bf16). One thread per (pixel, 8 channels).
// ---------------------------------------------------------------------------
__global__ __launch_bounds__(256) void dwconv5x5(
    const u16* __restrict__ vb, const float* __restrict__ cw,
    const float* __restrict__ cb, u16* __restrict__ lepeb)
{
    size_t tid = (size_t)blockIdx.x * 256 + threadIdx.x;   // [0, M_*32)
    int c8 = (int)(tid & 31);
    size_t pix = tid >> 5;
    int w = (int)(pix % S_);
    size_t tmp = pix / S_;
    int h = (int)(tmp % S_);
    int b = (int)(tmp / S_);
    int c0 = c8 * 8;

    float a[8];
#pragma unroll
    for (int q = 0; q < 8; ++q) a[q] = cb[c0 + q];
#pragma unroll
    for (int dy = -2; dy <= 2; ++dy) {
        int hy = h + dy;
        if (hy < 0 || hy >= S_) continue;
#pragma unroll
        for (int dx = -2; dx <= 2; ++dx) {
            int wx = w + dx;
            if (wx < 0 || wx >= S_) continue;
            int4 raw = *(const int4*)(vb + (((size_t)b * S_ + hy) * S_ + wx) * C_ + c0);
            const u16* e = (const u16*)&raw;
            const float* wp = cw + (size_t)((dy + 2) * 5 + (dx + 2)) * C_ + c0;
#pragma unroll
            for (int q = 0; q < 8; ++q) a[q] = fmaf(b2f(e[q]), wp[q], a[q]);
        }
    }
    u16 o[8];
#pragma unroll
    for (int q = 0; q < 8; ++q) o[q] = f2b(a[q]);
    *(int4*)(lepeb + pix * C_ + c0) = *(int4*)o;
}

// ---------------------------------------------------------------------------
// axial<HM>: MFMA axial attention with LOG-softmax.
//  HM=0 (width):  V-in = v (bf16), out = v1 (fp32, d_out), A single-bf16 PV
//  HM=1 (height): V-in = v1 (fp32, hi/lo split), out = out2 (bf16, q-buffer),
//                 A hi/lo split -> fp32-exact PV on the large v1 values.
// Block = (b, o, head), 128 thr = 2 waves, each wave 3 query-groups of 16.
// S^T = mfma(K-frag, Q-frag): lane holds S[query=l16][keys kg*4+r+16f];
// log-softmax reduce over the 4-lane kg group via shfl_xor(16,32).
// ---------------------------------------------------------------------------
template<int HM>
__global__ __launch_bounds__(128, 3) void axial(
    const u16* __restrict__ qb, const u16* __restrict__ kb,
    const void* __restrict__ vin, void* __restrict__ vout,
    int ofac, int pstride)
{
    __shared__ u16 sQ[96][56];
    __shared__ u16 sK[96][56];
    __shared__ u16 sVT[HM + 1][32][104];
    __shared__ u16 sAh[2][16][40];
    __shared__ u16 sAl[2][16][40];

    const int t = threadIdx.x;
    const int wave = t >> 6, lane = t & 63;
    const int l16 = lane & 15, kg = lane >> 4;

    const int n = blockIdx.x & 7;
    const int o = (blockIdx.x >> 3) % 96;
    const int b = blockIdx.x / (8 * 96);
    const size_t base = ((size_t)b * 9216 + (size_t)o * ofac) * C_ + n * D_;

    // stage Q, K tiles (96 x 32 bf16)
    if (t < 96) {
        const u16* gq = qb + base + (size_t)t * pstride;
        const u16* gk = kb + base + (size_t)t * pstride;
#pragma unroll
        for (int c = 0; c < 4; ++c) {
            *(int4*)&sQ[t][c * 8] = *(const int4*)(gq + c * 8);
            *(int4*)&sK[t][c * 8] = *(const int4*)(gk + c * 8);
        }
    }
    // stage V^T [d][j]
    if (HM == 0) {
        const u16* vb = (const u16*)vin;
#pragma unroll
        for (int p = 0; p < 3; ++p) {
            int j = p * 32 + (t >> 2);
            int dc = (t & 3) * 8;
            int4 raw = *(const int4*)(vb + base + (size_t)j * pstride + dc);
            const u16* e = (const u16*)&raw;
#pragma unroll
            for (int q = 0; q < 8; ++q) sVT[0][dc + q][j] = e[q];
        }
    } else {
        const float* v1 = (const float*)vin;
#pragma unroll
        for (int p = 0; p < 6; ++p) {
            int j = p * 16 + (t >> 3);
            int db = (t & 7) * 4;
            float4 f = *(const float4*)(v1 + base + (size_t)j * pstride + db);
            float fv[4] = { f.x, f.y, f.z, f.w };
#pragma unroll
            for (int q = 0; q < 4; ++q) {
                u16 hi = f2b(fv[q]);
                sVT[0][db + q][j] = hi;
                sVT[HM][db + q][j] = f2b(fv[q] - b2f(hi));
            }
        }
    }
    __syncthreads();

    // K fragments: rows = keys 16f + l16, cols = d kg*8..kg*8+7
    bf16x8 kf[6];
#pragma unroll
    for (int f = 0; f < 6; ++f)
        kf[f] = *(const bf16x8*)&sK[f * 16 + l16][kg * 8];

    const f32x4 zero = {0.f, 0.f, 0.f, 0.f};

    for (int p = 0; p < 3; ++p) {
        const int g = wave * 3 + p;            // query group: rows g*16..g*16+15
        bf16x8 qf = *(const bf16x8*)&sQ[g * 16 + l16][kg * 8];
        f32x4 s[6];
#pragma unroll
        for (int f = 0; f < 6; ++f)
            s[f] = __builtin_amdgcn_mfma_f32_16x16x32_bf16(kf[f], qf, zero, 0, 0, 0);
        // lane (l16, kg) holds S[query g*16+l16][key 16f + kg*4 + r]

        float m = s[0][0];
#pragma unroll
        for (int f = 0; f < 6; ++f)
#pragma unroll
            for (int r = 0; r < 4; ++r) m = fmaxf(m, s[f][r]);
        m = fmaxf(m, __shfl_xor(m, 16));
        m = fmaxf(m, __shfl_xor(m, 32));
        float l = 0.f;
#pragma unroll
        for (int f = 0; f < 6; ++f)
#pragma unroll
            for (int r = 0; r < 4; ++r) l += __expf(s[f][r] - m);
        l += __shfl_xor(l, 16);
        l += __shfl_xor(l, 32);
        float lse = m + __logf(l);

        u16 ah[6][4], al[6][4];
#pragma unroll
        for (int f = 0; f < 6; ++f)
#pragma unroll
            for (int r = 0; r < 4; ++r) {
                float a = s[f][r] - lse;
                ah[f][r] = f2b(a);
                if (HM) al[f][r] = f2b(a - b2f(ah[f][r]));
            }

        f32x4 pacc[2] = { zero, zero };
#pragma unroll
        for (int c = 0; c < 3; ++c) {          // key chunks of 32
            __syncthreads();                   // prior chunk reads done (both waves)
#pragma unroll
            for (int fi = 0; fi < 2; ++fi)
#pragma unroll
                for (int r = 0; r < 4; ++r) {
                    int col = fi * 16 + kg * 4 + r;
                    sAh[wave][l16][col] = ah[2 * c + fi][r];
                    if (HM) sAl[wave][l16][col] = al[2 * c + fi][r];
                }
            __syncthreads();
            bf16x8 ahf = *(const bf16x8*)&sAh[wave][l16][kg * 8];
            bf16x8 alf;
            if (HM) alf = *(const bf16x8*)&sAl[wave][l16][kg * 8];
#pragma unroll
            for (int nf = 0; nf < 2; ++nf) {
                bf16x8 vt = *(const bf16x8*)&sVT[0][nf * 16 + l16][c * 32 + kg * 8];
                pacc[nf] = __builtin_amdgcn_mfma_f32_16x16x32_bf16(ahf, vt, pacc[nf], 0, 0, 0);
                if (HM) {
                    bf16x8 vtl = *(const bf16x8*)&sVT[HM][nf * 16 + l16][c * 32 + kg * 8];
                    pacc[nf] = __builtin_amdgcn_mfma_f32_16x16x32_bf16(ahf, vtl, pacc[nf], 0, 0, 0);
                    pacc[nf] = __builtin_amdgcn_mfma_f32_16x16x32_bf16(alf, vt, pacc[nf], 0, 0, 0);
                }
            }
        }

        // store: row = query g*16 + kg*4 + r, col d = nf*16 + l16
#pragma unroll
        for (int nf = 0; nf < 2; ++nf)
#pragma unroll
            for (int r = 0; r < 4; ++r) {
                int qi = g * 16 + kg * 4 + r;
                size_t off = base + (size_t)qi * pstride + nf * 16 + l16;
                if (HM == 0) ((float*)vout)[off] = pacc[nf][r];
                else         ((u16*)vout)[off] = f2b(pacc[nf][r]);
            }
    }
}

// ---------------------------------------------------------------------------
// out_mfma: out = (out2 + lepe) @ Wo + bo; A inputs both bf16.
// ---------------------------------------------------------------------------
__global__ __launch_bounds__(256, 2) void out_mfma(
    const u16* __restrict__ o2b, const u16* __restrict__ lepeb,
    const u16* __restrict__ WoT, const float* __restrict__ bo,
    float* __restrict__ out)
{
    __shared__ u16 sA[128][72];
    __shared__ u16 sB[128][72];

    const int t = threadIdx.x;
    const int colbase = blockIdx.x * 128;
    const int m0 = blockIdx.y * 128;
    const int wave = t >> 6, lane = t & 63;
    const int wr = wave >> 1, wc = wave & 1;
    const int l16 = lane & 15, kg = lane >> 4;
    const int ra = t >> 1, ha = t & 1;

    f32x4 acc[4][4];
#pragma unroll
    for (int i = 0; i < 4; ++i)
#pragma unroll
        for (int j = 0; j < 4; ++j) acc[i][j] = (f32x4){0.f, 0.f, 0.f, 0.f};

    for (int k0 = 0; k0 < 256; k0 += 64) {
        const u16* gA = o2b + (size_t)(m0 + ra) * C_ + k0 + ha * 32;
        const u16* gL = lepeb + (size_t)(m0 + ra) * C_ + k0 + ha * 32;
        const u16* gB = WoT + (size_t)(colbase + ra) * C_ + k0 + ha * 32;
#pragma unroll
        for (int i = 0; i < 4; ++i) {
            int4 r0 = *(const int4*)(gA + i * 8);
            int4 r1 = *(const int4*)(gL + i * 8);
            const u16* e0 = (const u16*)&r0;
            const u16* e1 = (const u16*)&r1;
            u16 sm[8];
#pragma unroll
            for (int q = 0; q < 8; ++q) sm[q] = f2b(b2f(e0[q]) + b2f(e1[q]));
            *(int4*)(&sA[ra][ha * 32 + i * 8]) = *(int4*)sm;
            *(int4*)(&sB[ra][ha * 32 + i * 8]) = *(const int4*)(gB + i * 8);
        }
        __syncthreads();
#pragma unroll
        for (int ks = 0; ks < 2; ++ks) {
            bf16x8 af[4], bf[4];
#pragma unroll
            for (int mi = 0; mi < 4; ++mi)
                af[mi] = *(const bf16x8*)(&sA[wr * 64 + mi * 16 + l16][ks * 32 + kg * 8]);
#pragma unroll
            for (int ni = 0; ni < 4; ++ni)
                bf[ni] = *(const bf16x8*)(&sB[wc * 64 + ni * 16 + l16][ks * 32 + kg * 8]);
#pragma unroll
            for (int mi = 0; mi < 4; ++mi)
#pragma unroll
                for (int ni = 0; ni < 4; ++ni)
                    acc[mi][ni] = __builtin_amdgcn_mfma_f32_16x16x32_bf16(
                        af[mi], bf[ni], acc[mi][ni], 0, 0, 0);
        }
        __syncthreads();
    }

#pragma unroll
    for (int mi = 0; mi < 4; ++mi)
#pragma unroll
        for (int ni = 0; ni < 4; ++ni) {
            int col = colbase + wc * 64 + ni * 16 + l16;
            float bv_ = bo[col];
#pragma unroll
            for (int r = 0; r < 4; ++r) {
                int row = m0 + wr * 64 + mi * 16 + kg * 4 + r;
                out[(size_t)row * 256 + col] = acc[mi][ni][r] + bv_;
            }
        }
}

extern "C" void kernel_launch(void* const* d_in, const int* in_sizes, int n_in,
                              void* d_out, int out_size, void* d_ws, size_t ws_size,
                              hipStream_t stream)
{
    const float* x   = (const float*)d_in[0];
    const float* enc = (const float*)d_in[1];
    const float* Wq  = (const float*)d_in[2];
    const float* bq  = (const float*)d_in[3];
    const float* Wk  = (const float*)d_in[4];
    const float* bk  = (const float*)d_in[5];
    const float* Wv  = (const float*)d_in[6];
    const float* bv  = (const float*)d_in[7];
    const float* cw  = (const float*)d_in[8];
    const float* cb  = (const float*)d_in[9];
    const float* Wo  = (const float*)d_in[10];
    const float* bo  = (const float*)d_in[11];

    u16* qbuf = (u16*)d_ws;           // SZ bf16
    u16* kbuf = qbuf + SZ;
    u16* vbuf = kbuf + SZ;
    u16* WT   = vbuf + SZ;            // 4 * 65536 bf16
    u16* xb   = WT + 4 * 65536;
    u16* lep  = xb + SZ;
    float* v1 = (float*)d_out;        // width-stage PV output lives in d_out

    prep_x<<<9216, 256, 0, stream>>>(x, xb);
    prep_w<<<1024, 256, 0, stream>>>(Wq, Wk, Wv, Wo, WT);
    proj_q<<<dim3(2, 576), 256, 0, stream>>>(xb, WT, bq, qbuf);
    proj_kv<<<dim3(2, 576), 256, 0, stream>>>(xb, enc, WT, bk, bv, kbuf, vbuf);
    dwconv5x5<<<M_ * 32 / 256, 256, 0, stream>>>(vbuf, cw, cb, lep);
    // width: o = image row, positions = w (stride C_)
    axial<0><<<B_ * 96 * NH_, 128, 0, stream>>>(qbuf, kbuf, vbuf, v1, 96, 256);
    // height: o = image col, positions = h (stride 96*C_); out2 -> qbuf (in place per-slice)
    axial<1><<<B_ * 96 * NH_, 128, 0, stream>>>(qbuf, kbuf, v1, qbuf, 1, 96 * 256);
    out_mfma<<<dim3(2, 576), 256, 0, stream>>>(qbuf, lep, WT + 3 * 65536, bo, (float*)d_out);
}

// Round 4
// 333.797 us; speedup vs baseline: 2.9864x; 1.0614x over previous
//
#include <hip/hip_runtime.h>

#define B_ 8
#define S_ 96
#define C_ 256
#define NH_ 8
#define D_ 32
#define M_ (B_*S_*S_)
static const size_t SZ = (size_t)M_ * C_;

typedef unsigned short u16;
typedef short bf16x8 __attribute__((ext_vector_type(8)));
typedef _Float16 hf8 __attribute__((ext_vector_type(8)));
typedef float f32x4 __attribute__((ext_vector_type(4)));

__device__ __forceinline__ u16 f2b(float f) {                // fp32 -> bf16 RNE
    unsigned u = __float_as_uint(f);
    return (u16)((u + 0x7FFFu + ((u >> 16) & 1u)) >> 16);
}
__device__ __forceinline__ float b2f(u16 h) { return __uint_as_float(((unsigned)h) << 16); }
__device__ __forceinline__ u16 f2h(float f) {                // fp32 -> f16 RNE
    _Float16 h = (_Float16)f;
    return __builtin_bit_cast(u16, h);
}

__device__ __forceinline__ void gload16(const u16* g, u16* l) {
    __builtin_amdgcn_global_load_lds(
        (const __attribute__((address_space(1))) u16*)g,
        (__attribute__((address_space(3))) u16*)l, 16, 0, 0);
}

// ---------------------------------------------------------------------------
// prep_x: x fp32 -> xb bf16 (8 elems/thread)
// ---------------------------------------------------------------------------
__global__ __launch_bounds__(256) void prep_x(
    const float* __restrict__ x, u16* __restrict__ xb)
{
    size_t base = ((size_t)blockIdx.x * 256 + threadIdx.x) * 8;
    float4 a = *(const float4*)(x + base);
    float4 b = *(const float4*)(x + base + 4);
    u16 o[8] = { f2b(a.x), f2b(a.y), f2b(a.z), f2b(a.w),
                 f2b(b.x), f2b(b.y), f2b(b.z), f2b(b.w) };
    *(int4*)(xb + base) = *(int4*)o;
}

// ---------------------------------------------------------------------------
// prep_w: W[k][n] fp32 -> WT[w][n][k] bf16 for q,k,v,o
// ---------------------------------------------------------------------------
__global__ __launch_bounds__(256) void prep_w(
    const float* __restrict__ Wq, const float* __restrict__ Wk,
    const float* __restrict__ Wv, const float* __restrict__ Wo,
    u16* __restrict__ WT)
{
    int id = blockIdx.x * 256 + threadIdx.x;
    int w = id >> 16;
    int r = id & 65535;
    int n = r >> 8;
    int kk = r & 255;
    const float* Wp = (w == 0) ? Wq : (w == 1) ? Wk : (w == 2) ? Wv : Wo;
    WT[(size_t)id] = f2b(Wp[(size_t)kk * 256 + n]);
}

// prep_cw: conv weights fp32 -> f16 (25*256 = 6400 elems), grid 25x256
__global__ __launch_bounds__(256) void prep_cw(
    const float* __restrict__ cw, u16* __restrict__ cwh)
{
    int id = blockIdx.x * 256 + threadIdx.x;
    cwh[id] = f2h(cw[id]);
}

// ---------------------------------------------------------------------------
// proj_q: q = bf16(xb @ Wq + bq). 128x128 tile, BK=64, global_load_lds w16,
// XOR-swizzled source (slot' = slot ^ (row&7)), linear LDS [128][64].
// ---------------------------------------------------------------------------
#define STAGE4(gbase, lds, k0)                                                  \
    _Pragma("unroll")                                                           \
    for (int i = 0; i < 4; ++i) {                                               \
        int row8 = wave * 32 + i * 8;                                           \
        gload16((gbase) + (size_t)(row8 + lrow) * C_ + (k0) + sslot * 8,        \
                (lds) + row8 * 64);                                             \
    }

__global__ __launch_bounds__(256, 3) void proj_q(
    const u16* __restrict__ xb, const u16* __restrict__ WT,
    const float* __restrict__ bq, u16* __restrict__ q)
{
    __shared__ u16 sA[128 * 64];
    __shared__ u16 sB[128 * 64];
    const int t = threadIdx.x;
    const int colbase = blockIdx.x * 128;
    const int m0 = blockIdx.y * 128;
    const int wave = t >> 6, lane = t & 63;
    const int wr = wave >> 1, wc = wave & 1;
    const int l16 = lane & 15, kg = lane >> 4;
    const int lrow = lane >> 3;
    const int sslot = (lane & 7) ^ lrow;

    const u16* gA = xb + (size_t)m0 * C_;
    const u16* gB = WT + (size_t)colbase * C_;

    f32x4 acc[4][4];
#pragma unroll
    for (int i = 0; i < 4; ++i)
#pragma unroll
        for (int j = 0; j < 4; ++j) acc[i][j] = (f32x4){0.f, 0.f, 0.f, 0.f};

    STAGE4(gA, sA, 0); STAGE4(gB, sB, 0);
    for (int k0 = 0; k0 < 256; k0 += 64) {
        __syncthreads();
#pragma unroll
        for (int ks = 0; ks < 2; ++ks) {
            bf16x8 af[4], bf[4];
#pragma unroll
            for (int mi = 0; mi < 4; ++mi) {
                int row = wr * 64 + mi * 16 + l16;
                int sl = (ks * 4 + kg) ^ (l16 & 7);
                af[mi] = *(const bf16x8*)(sA + row * 64 + sl * 8);
            }
#pragma unroll
            for (int ni = 0; ni < 4; ++ni) {
                int row = wc * 64 + ni * 16 + l16;
                int sl = (ks * 4 + kg) ^ (l16 & 7);
                bf[ni] = *(const bf16x8*)(sB + row * 64 + sl * 8);
            }
#pragma unroll
            for (int mi = 0; mi < 4; ++mi)
#pragma unroll
                for (int ni = 0; ni < 4; ++ni)
                    acc[mi][ni] = __builtin_amdgcn_mfma_f32_16x16x32_bf16(
                        af[mi], bf[ni], acc[mi][ni], 0, 0, 0);
        }
        __syncthreads();
        if (k0 < 192) { STAGE4(gA, sA, k0 + 64); STAGE4(gB, sB, k0 + 64); }
    }

#pragma unroll
    for (int mi = 0; mi < 4; ++mi)
#pragma unroll
        for (int ni = 0; ni < 4; ++ni) {
            int col = colbase + wc * 64 + ni * 16 + l16;
            float bqv = bq[col];
#pragma unroll
            for (int r = 0; r < 4; ++r) {
                int row = m0 + wr * 64 + mi * 16 + kg * 4 + r;
                q[(size_t)row * 256 + col] = f2b(acc[mi][ni][r] + bqv);
            }
        }
}

// ---------------------------------------------------------------------------
// proj_kv: k = bf16((xb@Wk + bk + enc)*scale); v = f16(xb@Wv + bv + enc).
// v in f16 feeds packed-f16 dwconv and f16-MFMA width-PV.
// ---------------------------------------------------------------------------
__global__ __launch_bounds__(256, 2) void proj_kv(
    const u16* __restrict__ xb, const float* __restrict__ enc,
    const u16* __restrict__ WT,
    const float* __restrict__ bk, const float* __restrict__ bv,
    u16* __restrict__ k, u16* __restrict__ v)
{
    __shared__ u16 sA[128 * 64];
    __shared__ u16 sB0[128 * 64];
    __shared__ u16 sB1[128 * 64];
    const int t = threadIdx.x;
    const int colbase = blockIdx.x * 128;
    const int m0 = blockIdx.y * 128;
    const int wave = t >> 6, lane = t & 63;
    const int wr = wave >> 1, wc = wave & 1;
    const int l16 = lane & 15, kg = lane >> 4;
    const int lrow = lane >> 3;
    const int sslot = (lane & 7) ^ lrow;

    const u16* gA = xb + (size_t)m0 * C_;
    const u16* gB0 = WT + 65536 + (size_t)colbase * C_;          // Wk^T
    const u16* gB1 = WT + 2 * 65536 + (size_t)colbase * C_;      // Wv^T

    f32x4 acck[4][4], accv[4][4];
#pragma unroll
    for (int i = 0; i < 4; ++i)
#pragma unroll
        for (int j = 0; j < 4; ++j) {
            acck[i][j] = (f32x4){0.f, 0.f, 0.f, 0.f};
            accv[i][j] = (f32x4){0.f, 0.f, 0.f, 0.f};
        }

    STAGE4(gA, sA, 0); STAGE4(gB0, sB0, 0); STAGE4(gB1, sB1, 0);
    for (int k0 = 0; k0 < 256; k0 += 64) {
        __syncthreads();
#pragma unroll
        for (int ks = 0; ks < 2; ++ks) {
            bf16x8 af[4], b0[4], b1[4];
#pragma unroll
            for (int mi = 0; mi < 4; ++mi) {
                int row = wr * 64 + mi * 16 + l16;
                int sl = (ks * 4 + kg) ^ (l16 & 7);
                af[mi] = *(const bf16x8*)(sA + row * 64 + sl * 8);
            }
#pragma unroll
            for (int ni = 0; ni < 4; ++ni) {
                int row = wc * 64 + ni * 16 + l16;
                int sl = (ks * 4 + kg) ^ (l16 & 7);
                b0[ni] = *(const bf16x8*)(sB0 + row * 64 + sl * 8);
                b1[ni] = *(const bf16x8*)(sB1 + row * 64 + sl * 8);
            }
#pragma unroll
            for (int mi = 0; mi < 4; ++mi)
#pragma unroll
                for (int ni = 0; ni < 4; ++ni) {
                    acck[mi][ni] = __builtin_amdgcn_mfma_f32_16x16x32_bf16(
                        af[mi], b0[ni], acck[mi][ni], 0, 0, 0);
                    accv[mi][ni] = __builtin_amdgcn_mfma_f32_16x16x32_bf16(
                        af[mi], b1[ni], accv[mi][ni], 0, 0, 0);
                }
        }
        __syncthreads();
        if (k0 < 192) { STAGE4(gA, sA, k0 + 64); STAGE4(gB0, sB0, k0 + 64); STAGE4(gB1, sB1, k0 + 64); }
    }

    const float SCALE = 0.17677669529663687f;
#pragma unroll
    for (int mi = 0; mi < 4; ++mi)
#pragma unroll
        for (int ni = 0; ni < 4; ++ni) {
            int col = colbase + wc * 64 + ni * 16 + l16;
            float bkv = bk[col], bvv = bv[col];
#pragma unroll
            for (int r = 0; r < 4; ++r) {
                int row = m0 + wr * 64 + mi * 16 + kg * 4 + r;
                size_t off = (size_t)row * 256 + col;
                float e = enc[off];
                k[off] = f2b((acck[mi][ni][r] + bkv + e) * SCALE);
                v[off] = f2h(accv[mi][ni][r] + bvv + e);
            }
        }
}

// ---------------------------------------------------------------------------
// dwconv5x5: v (f16) -> lepe (bf16) via packed f16 math (v_pk_fma_f16).
// One thread per (pixel, 8 channels); weights preconverted to f16.
// ---------------------------------------------------------------------------
__global__ __launch_bounds__(256) void dwconv5x5(
    const u16* __restrict__ vh, const u16* __restrict__ cwh,
    const float* __restrict__ cb, u16* __restrict__ lepeb)
{
    size_t tid = (size_t)blockIdx.x * 256 + threadIdx.x;   // [0, M_*32)
    int c8 = (int)(tid & 31);
    size_t pix = tid >> 5;
    int w = (int)(pix % S_);
    size_t tmp = pix / S_;
    int h = (int)(tmp % S_);
    int b = (int)(tmp / S_);
    int c0 = c8 * 8;

    hf8 acc;
#pragma unroll
    for (int q = 0; q < 8; ++q) acc[q] = (_Float16)0.f;

#pragma unroll
    for (int dy = -2; dy <= 2; ++dy) {
        int hy = h + dy;
        if (hy < 0 || hy >= S_) continue;
#pragma unroll
        for (int dx = -2; dx <= 2; ++dx) {
            int wx = w + dx;
            if (wx < 0 || wx >= S_) continue;
            hf8 vv = *(const hf8*)(vh + (((size_t)b * S_ + hy) * S_ + wx) * C_ + c0);
            hf8 ww = *(const hf8*)(cwh + (size_t)((dy + 2) * 5 + (dx + 2)) * C_ + c0);
            acc += vv * ww;                      // packed f16 fma
        }
    }
    float4 cb0 = *(const float4*)(cb + c0);
    float4 cb1 = *(const float4*)(cb + c0 + 4);
    float cbv[8] = { cb0.x, cb0.y, cb0.z, cb0.w, cb1.x, cb1.y, cb1.z, cb1.w };
    u16 o[8];
#pragma unroll
    for (int q = 0; q < 8; ++q) o[q] = f2b((float)acc[q] + cbv[q]);
    *(int4*)(lepeb + pix * C_ + c0) = *(int4*)o;
}

// ---------------------------------------------------------------------------
// axial<HM>: MFMA axial attention with LOG-softmax.
//  HM=0 (width):  V-in = v (f16), out = v1 (fp32, d_out), A f16, PV f16 MFMA
//  HM=1 (height): V-in = v1 (fp32, hi/lo bf16 split), out = out2 (bf16,
//                 q-buffer), A hi/lo split -> near-fp32 PV.
// sAh/sAl are wave-private LDS scratch: no barriers needed in the PV loop
// (within-wave ds ordering is guaranteed; buffers indexed by [wave]).
// ---------------------------------------------------------------------------
template<int HM>
__global__ __launch_bounds__(128, 3) void axial(
    const u16* __restrict__ qb, const u16* __restrict__ kb,
    const void* __restrict__ vin, void* __restrict__ vout,
    int ofac, int pstride)
{
    __shared__ u16 sQ[96][56];
    __shared__ u16 sK[96][56];
    __shared__ u16 sVT[HM + 1][32][104];
    __shared__ u16 sAh[2][16][40];
    __shared__ u16 sAl[2][16][40];

    const int t = threadIdx.x;
    const int wave = t >> 6, lane = t & 63;
    const int l16 = lane & 15, kg = lane >> 4;

    const int n = blockIdx.x & 7;
    const int o = (blockIdx.x >> 3) % 96;
    const int b = blockIdx.x / (8 * 96);
    const size_t base = ((size_t)b * 9216 + (size_t)o * ofac) * C_ + n * D_;

    // stage Q, K tiles (96 x 32 bf16)
    if (t < 96) {
        const u16* gq = qb + base + (size_t)t * pstride;
        const u16* gk = kb + base + (size_t)t * pstride;
#pragma unroll
        for (int c = 0; c < 4; ++c) {
            *(int4*)&sQ[t][c * 8] = *(const int4*)(gq + c * 8);
            *(int4*)&sK[t][c * 8] = *(const int4*)(gk + c * 8);
        }
    }
    // stage V^T [d][j]
    if (HM == 0) {
        const u16* vb = (const u16*)vin;
#pragma unroll
        for (int p = 0; p < 3; ++p) {
            int j = p * 32 + (t >> 2);
            int dc = (t & 3) * 8;
            int4 raw = *(const int4*)(vb + base + (size_t)j * pstride + dc);
            const u16* e = (const u16*)&raw;
#pragma unroll
            for (int q = 0; q < 8; ++q) sVT[0][dc + q][j] = e[q];
        }
    } else {
        const float* v1 = (const float*)vin;
#pragma unroll
        for (int p = 0; p < 6; ++p) {
            int j = p * 16 + (t >> 3);
            int db = (t & 7) * 4;
            float4 f = *(const float4*)(v1 + base + (size_t)j * pstride + db);
            float fv[4] = { f.x, f.y, f.z, f.w };
#pragma unroll
            for (int q = 0; q < 4; ++q) {
                u16 hi = f2b(fv[q]);
                sVT[0][db + q][j] = hi;
                sVT[HM][db + q][j] = f2b(fv[q] - b2f(hi));
            }
        }
    }
    __syncthreads();

    // K fragments: rows = keys 16f + l16, cols = d kg*8..kg*8+7
    bf16x8 kf[6];
#pragma unroll
    for (int f = 0; f < 6; ++f)
        kf[f] = *(const bf16x8*)&sK[f * 16 + l16][kg * 8];

    const f32x4 zero = {0.f, 0.f, 0.f, 0.f};

    for (int p = 0; p < 3; ++p) {
        const int g = wave * 3 + p;            // query group: rows g*16..g*16+15
        bf16x8 qf = *(const bf16x8*)&sQ[g * 16 + l16][kg * 8];
        f32x4 s[6];
#pragma unroll
        for (int f = 0; f < 6; ++f)
            s[f] = __builtin_amdgcn_mfma_f32_16x16x32_bf16(kf[f], qf, zero, 0, 0, 0);
        // lane (l16, kg) holds S[query g*16+l16][key 16f + kg*4 + r]

        float m = s[0][0];
#pragma unroll
        for (int f = 0; f < 6; ++f)
#pragma unroll
            for (int r = 0; r < 4; ++r) m = fmaxf(m, s[f][r]);
        m = fmaxf(m, __shfl_xor(m, 16));
        m = fmaxf(m, __shfl_xor(m, 32));
        float l = 0.f;
#pragma unroll
        for (int f = 0; f < 6; ++f)
#pragma unroll
            for (int r = 0; r < 4; ++r) l += __expf(s[f][r] - m);
        l += __shfl_xor(l, 16);
        l += __shfl_xor(l, 32);
        float lse = m + __logf(l);

        u16 ah[6][4], al[6][4];
#pragma unroll
        for (int f = 0; f < 6; ++f)
#pragma unroll
            for (int r = 0; r < 4; ++r) {
                float a = s[f][r] - lse;
                ah[f][r] = (HM == 0) ? f2h(a) : f2b(a);
                if (HM) al[f][r] = f2b(a - b2f(ah[f][r]));
            }

        f32x4 pacc[2] = { zero, zero };
#pragma unroll
        for (int c = 0; c < 3; ++c) {          // key chunks of 32
#pragma unroll
            for (int fi = 0; fi < 2; ++fi)
#pragma unroll
                for (int r = 0; r < 4; ++r) {
                    int col = fi * 16 + kg * 4 + r;
                    sAh[wave][l16][col] = ah[2 * c + fi][r];
                    if (HM) sAl[wave][l16][col] = al[2 * c + fi][r];
                }
            if (HM == 0) {
                hf8 ahf = *(const hf8*)&sAh[wave][l16][kg * 8];
#pragma unroll
                for (int nf = 0; nf < 2; ++nf) {
                    hf8 vt = *(const hf8*)&sVT[0][nf * 16 + l16][c * 32 + kg * 8];
                    pacc[nf] = __builtin_amdgcn_mfma_f32_16x16x32_f16(ahf, vt, pacc[nf], 0, 0, 0);
                }
            } else {
                bf16x8 ahf = *(const bf16x8*)&sAh[wave][l16][kg * 8];
                bf16x8 alf = *(const bf16x8*)&sAl[wave][l16][kg * 8];
#pragma unroll
                for (int nf = 0; nf < 2; ++nf) {
                    bf16x8 vt = *(const bf16x8*)&sVT[0][nf * 16 + l16][c * 32 + kg * 8];
                    bf16x8 vtl = *(const bf16x8*)&sVT[HM][nf * 16 + l16][c * 32 + kg * 8];
                    pacc[nf] = __builtin_amdgcn_mfma_f32_16x16x32_bf16(ahf, vt, pacc[nf], 0, 0, 0);
                    pacc[nf] = __builtin_amdgcn_mfma_f32_16x16x32_bf16(ahf, vtl, pacc[nf], 0, 0, 0);
                    pacc[nf] = __builtin_amdgcn_mfma_f32_16x16x32_bf16(alf, vt, pacc[nf], 0, 0, 0);
                }
            }
        }

        // store: row = query g*16 + kg*4 + r, col d = nf*16 + l16
#pragma unroll
        for (int nf = 0; nf < 2; ++nf)
#pragma unroll
            for (int r = 0; r < 4; ++r) {
                int qi = g * 16 + kg * 4 + r;
                size_t off = base + (size_t)qi * pstride + nf * 16 + l16;
                if (HM == 0) ((float*)vout)[off] = pacc[nf][r];
                else         ((u16*)vout)[off] = f2b(pacc[nf][r]);
            }
    }
}

// ---------------------------------------------------------------------------
// out_mfma: out = (out2 + lepe) @ Wo + bo; A inputs both bf16.
// ---------------------------------------------------------------------------
__global__ __launch_bounds__(256, 2) void out_mfma(
    const u16* __restrict__ o2b, const u16* __restrict__ lepeb,
    const u16* __restrict__ WoT, const float* __restrict__ bo,
    float* __restrict__ out)
{
    __shared__ u16 sA[128][72];
    __shared__ u16 sB[128][72];

    const int t = threadIdx.x;
    const int colbase = blockIdx.x * 128;
    const int m0 = blockIdx.y * 128;
    const int wave = t >> 6, lane = t & 63;
    const int wr = wave >> 1, wc = wave & 1;
    const int l16 = lane & 15, kg = lane >> 4;
    const int ra = t >> 1, ha = t & 1;

    f32x4 acc[4][4];
#pragma unroll
    for (int i = 0; i < 4; ++i)
#pragma unroll
        for (int j = 0; j < 4; ++j) acc[i][j] = (f32x4){0.f, 0.f, 0.f, 0.f};

    for (int k0 = 0; k0 < 256; k0 += 64) {
        const u16* gA = o2b + (size_t)(m0 + ra) * C_ + k0 + ha * 32;
        const u16* gL = lepeb + (size_t)(m0 + ra) * C_ + k0 + ha * 32;
        const u16* gB = WoT + (size_t)(colbase + ra) * C_ + k0 + ha * 32;
#pragma unroll
        for (int i = 0; i < 4; ++i) {
            int4 r0 = *(const int4*)(gA + i * 8);
            int4 r1 = *(const int4*)(gL + i * 8);
            const u16* e0 = (const u16*)&r0;
            const u16* e1 = (const u16*)&r1;
            u16 sm[8];
#pragma unroll
            for (int q = 0; q < 8; ++q) sm[q] = f2b(b2f(e0[q]) + b2f(e1[q]));
            *(int4*)(&sA[ra][ha * 32 + i * 8]) = *(int4*)sm;
            *(int4*)(&sB[ra][ha * 32 + i * 8]) = *(const int4*)(gB + i * 8);
        }
        __syncthreads();
#pragma unroll
        for (int ks = 0; ks < 2; ++ks) {
            bf16x8 af[4], bf[4];
#pragma unroll
            for (int mi = 0; mi < 4; ++mi)
                af[mi] = *(const bf16x8*)(&sA[wr * 64 + mi * 16 + l16][ks * 32 + kg * 8]);
#pragma unroll
            for (int ni = 0; ni < 4; ++ni)
                bf[ni] = *(const bf16x8*)(&sB[wc * 64 + ni * 16 + l16][ks * 32 + kg * 8]);
#pragma unroll
            for (int mi = 0; mi < 4; ++mi)
#pragma unroll
                for (int ni = 0; ni < 4; ++ni)
                    acc[mi][ni] = __builtin_amdgcn_mfma_f32_16x16x32_bf16(
                        af[mi], bf[ni], acc[mi][ni], 0, 0, 0);
        }
        __syncthreads();
    }

#pragma unroll
    for (int mi = 0; mi < 4; ++mi)
#pragma unroll
        for (int ni = 0; ni < 4; ++ni) {
            int col = colbase + wc * 64 + ni * 16 + l16;
            float bv_ = bo[col];
#pragma unroll
            for (int r = 0; r < 4; ++r) {
                int row = m0 + wr * 64 + mi * 16 + kg * 4 + r;
                out[(size_t)row * 256 + col] = acc[mi][ni][r] + bv_;
            }
        }
}

extern "C" void kernel_launch(void* const* d_in, const int* in_sizes, int n_in,
                              void* d_out, int out_size, void* d_ws, size_t ws_size,
                              hipStream_t stream)
{
    const float* x   = (const float*)d_in[0];
    const float* enc = (const float*)d_in[1];
    const float* Wq  = (const float*)d_in[2];
    const float* bq  = (const float*)d_in[3];
    const float* Wk  = (const float*)d_in[4];
    const float* bk  = (const float*)d_in[5];
    const float* Wv  = (const float*)d_in[6];
    const float* bv  = (const float*)d_in[7];
    const float* cw  = (const float*)d_in[8];
    const float* cb  = (const float*)d_in[9];
    const float* Wo  = (const float*)d_in[10];
    const float* bo  = (const float*)d_in[11];

    u16* qbuf = (u16*)d_ws;            // SZ bf16 (later out2)
    u16* kbuf = qbuf + SZ;             // SZ bf16
    u16* vbuf = kbuf + SZ;             // SZ f16
    u16* WT   = vbuf + SZ;             // 4 * 65536 bf16
    u16* cwh  = WT + 4 * 65536;        // 6400 f16
    u16* xb   = cwh + 6400;            // SZ bf16
    u16* lep  = xb + SZ;               // SZ bf16
    float* v1 = (float*)d_out;         // width-stage PV output lives in d_out

    prep_x<<<9216, 256, 0, stream>>>(x, xb);
    prep_w<<<1024, 256, 0, stream>>>(Wq, Wk, Wv, Wo, WT);
    prep_cw<<<25, 256, 0, stream>>>(cw, cwh);
    proj_q<<<dim3(2, 576), 256, 0, stream>>>(xb, WT, bq, qbuf);
    proj_kv<<<dim3(2, 576), 256, 0, stream>>>(xb, enc, WT, bk, bv, kbuf, vbuf);
    dwconv5x5<<<M_ * 32 / 256, 256, 0, stream>>>(vbuf, cwh, cb, lep);
    // width: o = image row, positions = w (stride C_)
    axial<0><<<B_ * 96 * NH_, 128, 0, stream>>>(qbuf, kbuf, vbuf, v1, 96, 256);
    // height: o = image col, positions = h (stride 96*C_); out2 -> qbuf (in place per-slice)
    axial<1><<<B_ * 96 * NH_, 128, 0, stream>>>(qbuf, kbuf, v1, qbuf, 1, 96 * 256);
    out_mfma<<<dim3(2, 576), 256, 0, stream>>>(qbuf, lep, WT + 3 * 65536, bo, (float*)d_out);
}

// Round 5
// 324.729 us; speedup vs baseline: 3.0698x; 1.0279x over previous
//
#include <hip/hip_runtime.h>

#define B_ 8
#define S_ 96
#define C_ 256
#define NH_ 8
#define D_ 32
#define M_ (B_*S_*S_)
static const size_t SZ = (size_t)M_ * C_;

typedef unsigned short u16;
typedef short bf16x8 __attribute__((ext_vector_type(8)));
typedef _Float16 hf8 __attribute__((ext_vector_type(8)));
typedef float f32x4 __attribute__((ext_vector_type(4)));

__device__ __forceinline__ u16 f2b(float f) {                // fp32 -> bf16 RNE
    unsigned u = __float_as_uint(f);
    return (u16)((u + 0x7FFFu + ((u >> 16) & 1u)) >> 16);
}
__device__ __forceinline__ float b2f(u16 h) { return __uint_as_float(((unsigned)h) << 16); }
__device__ __forceinline__ u16 f2h(float f) {
    _Float16 h = (_Float16)f;
    return __builtin_bit_cast(u16, h);
}

__device__ __forceinline__ void gload16(const u16* g, u16* l) {
    __builtin_amdgcn_global_load_lds(
        (const __attribute__((address_space(1))) u16*)g,
        (__attribute__((address_space(3))) u16*)l, 16, 0, 0);
}

// rotate-swizzle of a 16B slot index (5 bits): spreads the 4 quad-columns
// (32-float apart) across distinct bank groups. Involution pair used on both
// write and read of the epilogue transpose buffer.
__device__ __forceinline__ int slotswz(int c4) { return ((c4 & 7) << 2) | (c4 >> 3); }

// ---------------------------------------------------------------------------
// prep_x: x fp32 -> xb bf16 (8 elems/thread)
// ---------------------------------------------------------------------------
__global__ __launch_bounds__(256) void prep_x(
    const float* __restrict__ x, u16* __restrict__ xb)
{
    size_t base = ((size_t)blockIdx.x * 256 + threadIdx.x) * 8;
    float4 a = *(const float4*)(x + base);
    float4 b = *(const float4*)(x + base + 4);
    u16 o[8] = { f2b(a.x), f2b(a.y), f2b(a.z), f2b(a.w),
                 f2b(b.x), f2b(b.y), f2b(b.z), f2b(b.w) };
    *(int4*)(xb + base) = *(int4*)o;
}

// ---------------------------------------------------------------------------
// prep_w: W[k][n] fp32 -> WT[w][n][k] bf16 for q,k,v,o
// ---------------------------------------------------------------------------
__global__ __launch_bounds__(256) void prep_w(
    const float* __restrict__ Wq, const float* __restrict__ Wk,
    const float* __restrict__ Wv, const float* __restrict__ Wo,
    u16* __restrict__ WT)
{
    int id = blockIdx.x * 256 + threadIdx.x;
    int w = id >> 16;
    int r = id & 65535;
    int n = r >> 8;
    int kk = r & 255;
    const float* Wp = (w == 0) ? Wq : (w == 1) ? Wk : (w == 2) ? Wv : Wo;
    WT[(size_t)id] = f2b(Wp[(size_t)kk * 256 + n]);
}

// prep_cw: conv weights fp32 -> f16
__global__ __launch_bounds__(256) void prep_cw(
    const float* __restrict__ cw, u16* __restrict__ cwh)
{
    int id = blockIdx.x * 256 + threadIdx.x;
    cwh[id] = f2h(cw[id]);
}

// ---------------------------------------------------------------------------
// proj_q: q = bf16(xb @ Wq + bq). 128x128 tile, BK=64, global_load_lds w16,
// XOR-swizzled source, linear LDS. Epilogue: LDS-transpose -> coalesced stores.
// ---------------------------------------------------------------------------
#define STAGE4(gbase, lds, k0)                                                  \
    _Pragma("unroll")                                                           \
    for (int i = 0; i < 4; ++i) {                                               \
        int row8 = wave * 32 + i * 8;                                           \
        gload16((gbase) + (size_t)(row8 + lrow) * C_ + (k0) + sslot * 8,        \
                (lds) + row8 * 64);                                             \
    }

__global__ __launch_bounds__(256, 3) void proj_q(
    const u16* __restrict__ xb, const u16* __restrict__ WT,
    const float* __restrict__ bq, u16* __restrict__ q)
{
    __shared__ u16 smem[2 * 8192 + 2048];       // sA, sB; reused as sT[64][132] f32
    u16* sA = smem;
    u16* sB = smem + 8192;
    const int t = threadIdx.x;
    const int colbase = blockIdx.x * 128;
    const int m0 = blockIdx.y * 128;
    const int wave = t >> 6, lane = t & 63;
    const int wr = wave >> 1, wc = wave & 1;
    const int l16 = lane & 15, kg = lane >> 4;
    const int lrow = lane >> 3;
    const int sslot = (lane & 7) ^ lrow;

    const u16* gA = xb + (size_t)m0 * C_;
    const u16* gB = WT + (size_t)colbase * C_;

    f32x4 acc[4][4];
#pragma unroll
    for (int i = 0; i < 4; ++i)
#pragma unroll
        for (int j = 0; j < 4; ++j) acc[i][j] = (f32x4){0.f, 0.f, 0.f, 0.f};

    STAGE4(gA, sA, 0); STAGE4(gB, sB, 0);
    for (int k0 = 0; k0 < 256; k0 += 64) {
        __syncthreads();
#pragma unroll
        for (int ks = 0; ks < 2; ++ks) {
            bf16x8 af[4], bf[4];
#pragma unroll
            for (int mi = 0; mi < 4; ++mi) {
                int row = wr * 64 + mi * 16 + l16;
                int sl = (ks * 4 + kg) ^ (l16 & 7);
                af[mi] = *(const bf16x8*)(sA + row * 64 + sl * 8);
            }
#pragma unroll
            for (int ni = 0; ni < 4; ++ni) {
                int row = wc * 64 + ni * 16 + l16;
                int sl = (ks * 4 + kg) ^ (l16 & 7);
                bf[ni] = *(const bf16x8*)(sB + row * 64 + sl * 8);
            }
#pragma unroll
            for (int mi = 0; mi < 4; ++mi)
#pragma unroll
                for (int ni = 0; ni < 4; ++ni)
                    acc[mi][ni] = __builtin_amdgcn_mfma_f32_16x16x32_bf16(
                        af[mi], bf[ni], acc[mi][ni], 0, 0, 0);
        }
        __syncthreads();
        if (k0 < 192) { STAGE4(gA, sA, k0 + 64); STAGE4(gB, sB, k0 + 64); }
    }

    // epilogue: LDS transpose -> coalesced bf16 stores
    float* sT = (float*)smem;                    // [64][132]
    const int erow = t >> 2;
    const int ecol = (t & 3) * 32;
#pragma unroll
    for (int half = 0; half < 2; ++half) {
        __syncthreads();
        if (wr == half) {
#pragma unroll
            for (int mi = 0; mi < 4; ++mi)
#pragma unroll
                for (int ni = 0; ni < 4; ++ni) {
                    int col = wc * 64 + ni * 16 + l16;
                    int colL = slotswz(col >> 2) * 4 + (col & 3);
#pragma unroll
                    for (int r = 0; r < 4; ++r)
                        sT[(mi * 16 + kg * 4 + r) * 132 + colL] = acc[mi][ni][r];
                }
        }
        __syncthreads();
        int grow = m0 + half * 64 + erow;
        u16 outv[32];
#pragma unroll
        for (int i = 0; i < 8; ++i) {
            int c4 = (t & 3) * 8 + i;
            float4 vv = *(float4*)&sT[erow * 132 + slotswz(c4) * 4];
            float4 bb = *(const float4*)(bq + colbase + ecol + i * 4);
            outv[i * 4 + 0] = f2b(vv.x + bb.x);
            outv[i * 4 + 1] = f2b(vv.y + bb.y);
            outv[i * 4 + 2] = f2b(vv.z + bb.z);
            outv[i * 4 + 3] = f2b(vv.w + bb.w);
        }
        u16* dst = q + (size_t)grow * 256 + colbase + ecol;
#pragma unroll
        for (int s = 0; s < 4; ++s) *(int4*)(dst + s * 8) = *(int4*)(outv + s * 8);
    }
}

// ---------------------------------------------------------------------------
// proj_kv: k = bf16((xb@Wk + bk + enc)*scale); v = f16(xb@Wv + bv + enc).
// Epilogue: 4 LDS-transpose passes (2 halves x {k,v}) -> vector enc loads +
// coalesced 64B stores.
// ---------------------------------------------------------------------------
__global__ __launch_bounds__(256, 2) void proj_kv(
    const u16* __restrict__ xb, const float* __restrict__ enc,
    const u16* __restrict__ WT,
    const float* __restrict__ bk, const float* __restrict__ bv,
    u16* __restrict__ k, u16* __restrict__ v)
{
    __shared__ u16 smem[3 * 8192];               // sA, sB0, sB1; reused as sT
    u16* sA = smem;
    u16* sB0 = smem + 8192;
    u16* sB1 = smem + 16384;
    const int t = threadIdx.x;
    const int colbase = blockIdx.x * 128;
    const int m0 = blockIdx.y * 128;
    const int wave = t >> 6, lane = t & 63;
    const int wr = wave >> 1, wc = wave & 1;
    const int l16 = lane & 15, kg = lane >> 4;
    const int lrow = lane >> 3;
    const int sslot = (lane & 7) ^ lrow;

    const u16* gA = xb + (size_t)m0 * C_;
    const u16* gB0 = WT + 65536 + (size_t)colbase * C_;
    const u16* gB1 = WT + 2 * 65536 + (size_t)colbase * C_;

    f32x4 acck[4][4], accv[4][4];
#pragma unroll
    for (int i = 0; i < 4; ++i)
#pragma unroll
        for (int j = 0; j < 4; ++j) {
            acck[i][j] = (f32x4){0.f, 0.f, 0.f, 0.f};
            accv[i][j] = (f32x4){0.f, 0.f, 0.f, 0.f};
        }

    STAGE4(gA, sA, 0); STAGE4(gB0, sB0, 0); STAGE4(gB1, sB1, 0);
    for (int k0 = 0; k0 < 256; k0 += 64) {
        __syncthreads();
#pragma unroll
        for (int ks = 0; ks < 2; ++ks) {
            bf16x8 af[4], b0[4], b1[4];
#pragma unroll
            for (int mi = 0; mi < 4; ++mi) {
                int row = wr * 64 + mi * 16 + l16;
                int sl = (ks * 4 + kg) ^ (l16 & 7);
                af[mi] = *(const bf16x8*)(sA + row * 64 + sl * 8);
            }
#pragma unroll
            for (int ni = 0; ni < 4; ++ni) {
                int row = wc * 64 + ni * 16 + l16;
                int sl = (ks * 4 + kg) ^ (l16 & 7);
                b0[ni] = *(const bf16x8*)(sB0 + row * 64 + sl * 8);
                b1[ni] = *(const bf16x8*)(sB1 + row * 64 + sl * 8);
            }
#pragma unroll
            for (int mi = 0; mi < 4; ++mi)
#pragma unroll
                for (int ni = 0; ni < 4; ++ni) {
                    acck[mi][ni] = __builtin_amdgcn_mfma_f32_16x16x32_bf16(
                        af[mi], b0[ni], acck[mi][ni], 0, 0, 0);
                    accv[mi][ni] = __builtin_amdgcn_mfma_f32_16x16x32_bf16(
                        af[mi], b1[ni], accv[mi][ni], 0, 0, 0);
                }
        }
        __syncthreads();
        if (k0 < 192) { STAGE4(gA, sA, k0 + 64); STAGE4(gB0, sB0, k0 + 64); STAGE4(gB1, sB1, k0 + 64); }
    }

    const float SCALE = 0.17677669529663687f;
    float* sT = (float*)smem;                    // [64][132] = 33792 B <= 49152
    const int erow = t >> 2;
    const int ecol = (t & 3) * 32;
#pragma unroll
    for (int half = 0; half < 2; ++half) {
#pragma unroll
        for (int mat = 0; mat < 2; ++mat) {
            __syncthreads();
            if (wr == half) {
                if (mat == 0) {
#pragma unroll
                    for (int mi = 0; mi < 4; ++mi)
#pragma unroll
                        for (int ni = 0; ni < 4; ++ni) {
                            int col = wc * 64 + ni * 16 + l16;
                            int colL = slotswz(col >> 2) * 4 + (col & 3);
#pragma unroll
                            for (int r = 0; r < 4; ++r)
                                sT[(mi * 16 + kg * 4 + r) * 132 + colL] = acck[mi][ni][r];
                        }
                } else {
#pragma unroll
                    for (int mi = 0; mi < 4; ++mi)
#pragma unroll
                        for (int ni = 0; ni < 4; ++ni) {
                            int col = wc * 64 + ni * 16 + l16;
                            int colL = slotswz(col >> 2) * 4 + (col & 3);
#pragma unroll
                            for (int r = 0; r < 4; ++r)
                                sT[(mi * 16 + kg * 4 + r) * 132 + colL] = accv[mi][ni][r];
                        }
                }
            }
            __syncthreads();
            int grow = m0 + half * 64 + erow;
            const float* ep = enc + (size_t)grow * 256 + colbase + ecol;
            const float* bp = (mat == 0 ? bk : bv) + colbase + ecol;
            u16 outv[32];
#pragma unroll
            for (int i = 0; i < 8; ++i) {
                int c4 = (t & 3) * 8 + i;
                float4 vv = *(float4*)&sT[erow * 132 + slotswz(c4) * 4];
                float4 ee = *(const float4*)(ep + i * 4);
                float4 bb = *(const float4*)(bp + i * 4);
                float r0 = vv.x + bb.x + ee.x;
                float r1 = vv.y + bb.y + ee.y;
                float r2 = vv.z + bb.z + ee.z;
                float r3 = vv.w + bb.w + ee.w;
                if (mat == 0) {
                    outv[i * 4 + 0] = f2b(r0 * SCALE);
                    outv[i * 4 + 1] = f2b(r1 * SCALE);
                    outv[i * 4 + 2] = f2b(r2 * SCALE);
                    outv[i * 4 + 3] = f2b(r3 * SCALE);
                } else {
                    outv[i * 4 + 0] = f2h(r0);
                    outv[i * 4 + 1] = f2h(r1);
                    outv[i * 4 + 2] = f2h(r2);
                    outv[i * 4 + 3] = f2h(r3);
                }
            }
            u16* dst = (mat == 0 ? k : v) + (size_t)grow * 256 + colbase + ecol;
#pragma unroll
            for (int s = 0; s < 4; ++s) *(int4*)(dst + s * 8) = *(int4*)(outv + s * 8);
        }
    }
}

// ---------------------------------------------------------------------------
// dwconv5x5: v (f16) -> lepe (bf16), packed f16 math, 4 output pixels/thread
// (register blocking along w: shared 5x8 window, 10 loads/output vs 25).
// thread -> (b, h, w0=4*wi, 8 channels). grid = M_/4*32/256 = 2304 blocks.
// ---------------------------------------------------------------------------
__global__ __launch_bounds__(256) void dwconv5x5(
    const u16* __restrict__ vh, const u16* __restrict__ cwh,
    const float* __restrict__ cb, u16* __restrict__ lepeb)
{
    size_t tid = (size_t)blockIdx.x * 256 + threadIdx.x;   // [0, 589824)
    int c8 = (int)(tid & 31);
    size_t rest = tid >> 5;                                // (b,h,wi)
    int wi = (int)(rest % 24);
    size_t tmp = rest / 24;
    int h = (int)(tmp % S_);
    int b = (int)(tmp / S_);
    int w0 = wi * 4;
    int c0 = c8 * 8;

    hf8 z;
#pragma unroll
    for (int q = 0; q < 8; ++q) z[q] = (_Float16)0.f;
    hf8 acc[4] = { z, z, z, z };

#pragma unroll
    for (int dy = -2; dy <= 2; ++dy) {
        int hy = h + dy;
        if (hy < 0 || hy >= S_) continue;
        const u16* rowp = vh + (((size_t)b * S_ + hy) * S_) * C_ + c0;
        hf8 vr[8];
#pragma unroll
        for (int i = 0; i < 8; ++i) {
            int c = w0 - 2 + i;
            vr[i] = (c >= 0 && c < S_) ? *(const hf8*)(rowp + (size_t)c * C_) : z;
        }
#pragma unroll
        for (int dx = 0; dx < 5; ++dx) {
            hf8 ww = *(const hf8*)(cwh + (size_t)((dy + 2) * 5 + dx) * C_ + c0);
#pragma unroll
            for (int r = 0; r < 4; ++r) acc[r] += vr[dx + r] * ww;
        }
    }

    float4 cb0 = *(const float4*)(cb + c0);
    float4 cb1 = *(const float4*)(cb + c0 + 4);
    float cbv[8] = { cb0.x, cb0.y, cb0.z, cb0.w, cb1.x, cb1.y, cb1.z, cb1.w };
    size_t pix0 = ((size_t)b * S_ + h) * S_ + w0;
#pragma unroll
    for (int r = 0; r < 4; ++r) {
        u16 o[8];
#pragma unroll
        for (int q = 0; q < 8; ++q) o[q] = f2b((float)acc[r][q] + cbv[q]);
        *(int4*)(lepeb + (pix0 + r) * C_ + c0) = *(int4*)o;
    }
}

// ---------------------------------------------------------------------------
// axial<HM>: MFMA axial attention with LOG-softmax (unchanged from R4).
// ---------------------------------------------------------------------------
template<int HM>
__global__ __launch_bounds__(128, 3) void axial(
    const u16* __restrict__ qb, const u16* __restrict__ kb,
    const void* __restrict__ vin, void* __restrict__ vout,
    int ofac, int pstride)
{
    __shared__ u16 sQ[96][56];
    __shared__ u16 sK[96][56];
    __shared__ u16 sVT[HM + 1][32][104];
    __shared__ u16 sAh[2][16][40];
    __shared__ u16 sAl[2][16][40];

    const int t = threadIdx.x;
    const int wave = t >> 6, lane = t & 63;
    const int l16 = lane & 15, kg = lane >> 4;

    const int n = blockIdx.x & 7;
    const int o = (blockIdx.x >> 3) % 96;
    const int b = blockIdx.x / (8 * 96);
    const size_t base = ((size_t)b * 9216 + (size_t)o * ofac) * C_ + n * D_;

    if (t < 96) {
        const u16* gq = qb + base + (size_t)t * pstride;
        const u16* gk = kb + base + (size_t)t * pstride;
#pragma unroll
        for (int c = 0; c < 4; ++c) {
            *(int4*)&sQ[t][c * 8] = *(const int4*)(gq + c * 8);
            *(int4*)&sK[t][c * 8] = *(const int4*)(gk + c * 8);
        }
    }
    if (HM == 0) {
        const u16* vb = (const u16*)vin;
#pragma unroll
        for (int p = 0; p < 3; ++p) {
            int j = p * 32 + (t >> 2);
            int dc = (t & 3) * 8;
            int4 raw = *(const int4*)(vb + base + (size_t)j * pstride + dc);
            const u16* e = (const u16*)&raw;
#pragma unroll
            for (int q = 0; q < 8; ++q) sVT[0][dc + q][j] = e[q];
        }
    } else {
        const float* v1 = (const float*)vin;
#pragma unroll
        for (int p = 0; p < 6; ++p) {
            int j = p * 16 + (t >> 3);
            int db = (t & 7) * 4;
            float4 f = *(const float4*)(v1 + base + (size_t)j * pstride + db);
            float fv[4] = { f.x, f.y, f.z, f.w };
#pragma unroll
            for (int q = 0; q < 4; ++q) {
                u16 hi = f2b(fv[q]);
                sVT[0][db + q][j] = hi;
                sVT[HM][db + q][j] = f2b(fv[q] - b2f(hi));
            }
        }
    }
    __syncthreads();

    bf16x8 kf[6];
#pragma unroll
    for (int f = 0; f < 6; ++f)
        kf[f] = *(const bf16x8*)&sK[f * 16 + l16][kg * 8];

    const f32x4 zero = {0.f, 0.f, 0.f, 0.f};

    for (int p = 0; p < 3; ++p) {
        const int g = wave * 3 + p;
        bf16x8 qf = *(const bf16x8*)&sQ[g * 16 + l16][kg * 8];
        f32x4 s[6];
#pragma unroll
        for (int f = 0; f < 6; ++f)
            s[f] = __builtin_amdgcn_mfma_f32_16x16x32_bf16(kf[f], qf, zero, 0, 0, 0);

        float m = s[0][0];
#pragma unroll
        for (int f = 0; f < 6; ++f)
#pragma unroll
            for (int r = 0; r < 4; ++r) m = fmaxf(m, s[f][r]);
        m = fmaxf(m, __shfl_xor(m, 16));
        m = fmaxf(m, __shfl_xor(m, 32));
        float l = 0.f;
#pragma unroll
        for (int f = 0; f < 6; ++f)
#pragma unroll
            for (int r = 0; r < 4; ++r) l += __expf(s[f][r] - m);
        l += __shfl_xor(l, 16);
        l += __shfl_xor(l, 32);
        float lse = m + __logf(l);

        u16 ah[6][4], al[6][4];
#pragma unroll
        for (int f = 0; f < 6; ++f)
#pragma unroll
            for (int r = 0; r < 4; ++r) {
                float a = s[f][r] - lse;
                ah[f][r] = (HM == 0) ? f2h(a) : f2b(a);
                if (HM) al[f][r] = f2b(a - b2f(ah[f][r]));
            }

        f32x4 pacc[2] = { zero, zero };
#pragma unroll
        for (int c = 0; c < 3; ++c) {
#pragma unroll
            for (int fi = 0; fi < 2; ++fi)
#pragma unroll
                for (int r = 0; r < 4; ++r) {
                    int col = fi * 16 + kg * 4 + r;
                    sAh[wave][l16][col] = ah[2 * c + fi][r];
                    if (HM) sAl[wave][l16][col] = al[2 * c + fi][r];
                }
            if (HM == 0) {
                hf8 ahf = *(const hf8*)&sAh[wave][l16][kg * 8];
#pragma unroll
                for (int nf = 0; nf < 2; ++nf) {
                    hf8 vt = *(const hf8*)&sVT[0][nf * 16 + l16][c * 32 + kg * 8];
                    pacc[nf] = __builtin_amdgcn_mfma_f32_16x16x32_f16(ahf, vt, pacc[nf], 0, 0, 0);
                }
            } else {
                bf16x8 ahf = *(const bf16x8*)&sAh[wave][l16][kg * 8];
                bf16x8 alf = *(const bf16x8*)&sAl[wave][l16][kg * 8];
#pragma unroll
                for (int nf = 0; nf < 2; ++nf) {
                    bf16x8 vt = *(const bf16x8*)&sVT[0][nf * 16 + l16][c * 32 + kg * 8];
                    bf16x8 vtl = *(const bf16x8*)&sVT[HM][nf * 16 + l16][c * 32 + kg * 8];
                    pacc[nf] = __builtin_amdgcn_mfma_f32_16x16x32_bf16(ahf, vt, pacc[nf], 0, 0, 0);
                    pacc[nf] = __builtin_amdgcn_mfma_f32_16x16x32_bf16(ahf, vtl, pacc[nf], 0, 0, 0);
                    pacc[nf] = __builtin_amdgcn_mfma_f32_16x16x32_bf16(alf, vt, pacc[nf], 0, 0, 0);
                }
            }
        }

#pragma unroll
        for (int nf = 0; nf < 2; ++nf)
#pragma unroll
            for (int r = 0; r < 4; ++r) {
                int qi = g * 16 + kg * 4 + r;
                size_t off = base + (size_t)qi * pstride + nf * 16 + l16;
                if (HM == 0) ((float*)vout)[off] = pacc[nf][r];
                else         ((u16*)vout)[off] = f2b(pacc[nf][r]);
            }
    }
}

// ---------------------------------------------------------------------------
// out_mfma: out = (out2 + lepe) @ Wo + bo; A inputs both bf16.
// ---------------------------------------------------------------------------
__global__ __launch_bounds__(256, 2) void out_mfma(
    const u16* __restrict__ o2b, const u16* __restrict__ lepeb,
    const u16* __restrict__ WoT, const float* __restrict__ bo,
    float* __restrict__ out)
{
    __shared__ u16 sA[128][72];
    __shared__ u16 sB[128][72];

    const int t = threadIdx.x;
    const int colbase = blockIdx.x * 128;
    const int m0 = blockIdx.y * 128;
    const int wave = t >> 6, lane = t & 63;
    const int wr = wave >> 1, wc = wave & 1;
    const int l16 = lane & 15, kg = lane >> 4;
    const int ra = t >> 1, ha = t & 1;

    f32x4 acc[4][4];
#pragma unroll
    for (int i = 0; i < 4; ++i)
#pragma unroll
        for (int j = 0; j < 4; ++j) acc[i][j] = (f32x4){0.f, 0.f, 0.f, 0.f};

    for (int k0 = 0; k0 < 256; k0 += 64) {
        const u16* gA = o2b + (size_t)(m0 + ra) * C_ + k0 + ha * 32;
        const u16* gL = lepeb + (size_t)(m0 + ra) * C_ + k0 + ha * 32;
        const u16* gB = WoT + (size_t)(colbase + ra) * C_ + k0 + ha * 32;
#pragma unroll
        for (int i = 0; i < 4; ++i) {
            int4 r0 = *(const int4*)(gA + i * 8);
            int4 r1 = *(const int4*)(gL + i * 8);
            const u16* e0 = (const u16*)&r0;
            const u16* e1 = (const u16*)&r1;
            u16 sm[8];
#pragma unroll
            for (int q = 0; q < 8; ++q) sm[q] = f2b(b2f(e0[q]) + b2f(e1[q]));
            *(int4*)(&sA[ra][ha * 32 + i * 8]) = *(int4*)sm;
            *(int4*)(&sB[ra][ha * 32 + i * 8]) = *(const int4*)(gB + i * 8);
        }
        __syncthreads();
#pragma unroll
        for (int ks = 0; ks < 2; ++ks) {
            bf16x8 af[4], bf[4];
#pragma unroll
            for (int mi = 0; mi < 4; ++mi)
                af[mi] = *(const bf16x8*)(&sA[wr * 64 + mi * 16 + l16][ks * 32 + kg * 8]);
#pragma unroll
            for (int ni = 0; ni < 4; ++ni)
                bf[ni] = *(const bf16x8*)(&sB[wc * 64 + ni * 16 + l16][ks * 32 + kg * 8]);
#pragma unroll
            for (int mi = 0; mi < 4; ++mi)
#pragma unroll
                for (int ni = 0; ni < 4; ++ni)
                    acc[mi][ni] = __builtin_amdgcn_mfma_f32_16x16x32_bf16(
                        af[mi], bf[ni], acc[mi][ni], 0, 0, 0);
        }
        __syncthreads();
    }

#pragma unroll
    for (int mi = 0; mi < 4; ++mi)
#pragma unroll
        for (int ni = 0; ni < 4; ++ni) {
            int col = colbase + wc * 64 + ni * 16 + l16;
            float bv_ = bo[col];
#pragma unroll
            for (int r = 0; r < 4; ++r) {
                int row = m0 + wr * 64 + mi * 16 + kg * 4 + r;
                out[(size_t)row * 256 + col] = acc[mi][ni][r] + bv_;
            }
        }
}

extern "C" void kernel_launch(void* const* d_in, const int* in_sizes, int n_in,
                              void* d_out, int out_size, void* d_ws, size_t ws_size,
                              hipStream_t stream)
{
    const float* x   = (const float*)d_in[0];
    const float* enc = (const float*)d_in[1];
    const float* Wq  = (const float*)d_in[2];
    const float* bq  = (const float*)d_in[3];
    const float* Wk  = (const float*)d_in[4];
    const float* bk  = (const float*)d_in[5];
    const float* Wv  = (const float*)d_in[6];
    const float* bv  = (const float*)d_in[7];
    const float* cw  = (const float*)d_in[8];
    const float* cb  = (const float*)d_in[9];
    const float* Wo  = (const float*)d_in[10];
    const float* bo  = (const float*)d_in[11];

    u16* qbuf = (u16*)d_ws;            // SZ bf16 (later out2)
    u16* kbuf = qbuf + SZ;             // SZ bf16
    u16* vbuf = kbuf + SZ;             // SZ f16
    u16* WT   = vbuf + SZ;             // 4 * 65536 bf16
    u16* cwh  = WT + 4 * 65536;        // 6400 f16
    u16* xb   = cwh + 6400;            // SZ bf16
    u16* lep  = xb + SZ;               // SZ bf16
    float* v1 = (float*)d_out;         // width-stage PV output lives in d_out

    prep_x<<<9216, 256, 0, stream>>>(x, xb);
    prep_w<<<1024, 256, 0, stream>>>(Wq, Wk, Wv, Wo, WT);
    prep_cw<<<25, 256, 0, stream>>>(cw, cwh);
    proj_q<<<dim3(2, 576), 256, 0, stream>>>(xb, WT, bq, qbuf);
    proj_kv<<<dim3(2, 576), 256, 0, stream>>>(xb, enc, WT, bk, bv, kbuf, vbuf);
    dwconv5x5<<<2304, 256, 0, stream>>>(vbuf, cwh, cb, lep);
    // width: o = image row, positions = w (stride C_)
    axial<0><<<B_ * 96 * NH_, 128, 0, stream>>>(qbuf, kbuf, vbuf, v1, 96, 256);
    // height: o = image col, positions = h (stride 96*C_); out2 -> qbuf (in place per-slice)
    axial<1><<<B_ * 96 * NH_, 128, 0, stream>>>(qbuf, kbuf, v1, qbuf, 1, 96 * 256);
    out_mfma<<<dim3(2, 576), 256, 0, stream>>>(qbuf, lep, WT + 3 * 65536, bo, (float*)d_out);
}

// Round 6
// 288.834 us; speedup vs baseline: 3.4513x; 1.1243x over previous
//
#include <hip/hip_runtime.h>

#define B_ 8
#define S_ 96
#define C_ 256
#define NH_ 8
#define D_ 32
#define M_ (B_*S_*S_)
static const size_t SZ = (size_t)M_ * C_;

typedef unsigned short u16;
typedef short bf16x8 __attribute__((ext_vector_type(8)));
typedef _Float16 hf8 __attribute__((ext_vector_type(8)));
typedef float f32x4 __attribute__((ext_vector_type(4)));

__device__ __forceinline__ u16 f2b(float f) {                // fp32 -> bf16 RNE
    unsigned u = __float_as_uint(f);
    return (u16)((u + 0x7FFFu + ((u >> 16) & 1u)) >> 16);
}
__device__ __forceinline__ float b2f(u16 h) { return __uint_as_float(((unsigned)h) << 16); }
__device__ __forceinline__ u16 f2h(float f) {
    _Float16 h = (_Float16)f;
    return __builtin_bit_cast(u16, h);
}

__device__ __forceinline__ void gload16(const u16* g, u16* l) {
    __builtin_amdgcn_global_load_lds(
        (const __attribute__((address_space(1))) u16*)g,
        (__attribute__((address_space(3))) u16*)l, 16, 0, 0);
}

// ---------------------------------------------------------------------------
// prep_x: x fp32 -> xb bf16 (8 elems/thread)
// ---------------------------------------------------------------------------
__global__ __launch_bounds__(256) void prep_x(
    const float* __restrict__ x, u16* __restrict__ xb)
{
    size_t base = ((size_t)blockIdx.x * 256 + threadIdx.x) * 8;
    float4 a = *(const float4*)(x + base);
    float4 b = *(const float4*)(x + base + 4);
    u16 o[8] = { f2b(a.x), f2b(a.y), f2b(a.z), f2b(a.w),
                 f2b(b.x), f2b(b.y), f2b(b.z), f2b(b.w) };
    *(int4*)(xb + base) = *(int4*)o;
}

// ---------------------------------------------------------------------------
// prep_w: W[k][n] fp32 -> WT[w][n][k] bf16 for q,k,v,o
// ---------------------------------------------------------------------------
__global__ __launch_bounds__(256) void prep_w(
    const float* __restrict__ Wq, const float* __restrict__ Wk,
    const float* __restrict__ Wv, const float* __restrict__ Wo,
    u16* __restrict__ WT)
{
    int id = blockIdx.x * 256 + threadIdx.x;
    int w = id >> 16;
    int r = id & 65535;
    int n = r >> 8;
    int kk = r & 255;
    const float* Wp = (w == 0) ? Wq : (w == 1) ? Wk : (w == 2) ? Wv : Wo;
    WT[(size_t)id] = f2b(Wp[(size_t)kk * 256 + n]);
}

// prep_cw: conv weights fp32 -> f16
__global__ __launch_bounds__(256) void prep_cw(
    const float* __restrict__ cw, u16* __restrict__ cwh)
{
    int id = blockIdx.x * 256 + threadIdx.x;
    cwh[id] = f2h(cw[id]);
}

// ---------------------------------------------------------------------------
// 2-phase double-buffered GEMM K-step staging: BK=32 (row = 64B), one buffer
// is 128x32 bf16 = 8KB. Per buffer: 2 gload16 waves-calls (wave covers 32
// rows). LDS dest linear (lane*16B == (lane>>2)*row + (lane&3)*slot). Read
// fragment bank pattern is 2-way aliased max -> free (m136). No swizzle.
// Loop shape (T3 minimum 2-phase): STAGE(next) -> compute(cur) -> barrier.
// ---------------------------------------------------------------------------
#define STG(lds, gbase, k0)                                                     \
    _Pragma("unroll")                                                           \
    for (int i_ = 0; i_ < 2; ++i_) {                                            \
        int r16 = wave * 32 + i_ * 16;                                          \
        gload16((gbase) + (size_t)(r16 + lrow) * C_ + (k0) + slot * 8,          \
                (lds) + r16 * 32);                                              \
    }

// ---------------------------------------------------------------------------
// proj_q: q = bf16(xb @ Wq + bq). 128x128 tile, BK=32 dbuf, 32KB LDS.
// ---------------------------------------------------------------------------
__global__ __launch_bounds__(256, 3) void proj_q(
    const u16* __restrict__ xb, const u16* __restrict__ WT,
    const float* __restrict__ bq, u16* __restrict__ q)
{
    __shared__ u16 sA[2 * 4096];
    __shared__ u16 sB[2 * 4096];
    const int t = threadIdx.x;
    const int colbase = blockIdx.x * 128;
    const int m0 = blockIdx.y * 128;
    const int wave = t >> 6, lane = t & 63;
    const int wr = wave >> 1, wc = wave & 1;
    const int l16 = lane & 15, kg = lane >> 4;
    const int lrow = lane >> 2, slot = lane & 3;

    const u16* gA = xb + (size_t)m0 * C_;
    const u16* gB = WT + (size_t)colbase * C_;

    f32x4 acc[4][4];
#pragma unroll
    for (int i = 0; i < 4; ++i)
#pragma unroll
        for (int j = 0; j < 4; ++j) acc[i][j] = (f32x4){0.f, 0.f, 0.f, 0.f};

    STG(sA, gA, 0); STG(sB, gB, 0);
    __syncthreads();
#pragma unroll
    for (int it = 0; it < 8; ++it) {
        const int cur = it & 1;
        if (it < 7) { STG(sA + (cur ^ 1) * 4096, gA, (it + 1) * 32);
                      STG(sB + (cur ^ 1) * 4096, gB, (it + 1) * 32); }
        bf16x8 af[4], bf[4];
#pragma unroll
        for (int mi = 0; mi < 4; ++mi)
            af[mi] = *(const bf16x8*)(sA + cur * 4096 + (wr * 64 + mi * 16 + l16) * 32 + kg * 8);
#pragma unroll
        for (int ni = 0; ni < 4; ++ni)
            bf[ni] = *(const bf16x8*)(sB + cur * 4096 + (wc * 64 + ni * 16 + l16) * 32 + kg * 8);
#pragma unroll
        for (int mi = 0; mi < 4; ++mi)
#pragma unroll
            for (int ni = 0; ni < 4; ++ni)
                acc[mi][ni] = __builtin_amdgcn_mfma_f32_16x16x32_bf16(
                    af[mi], bf[ni], acc[mi][ni], 0, 0, 0);
        if (it < 7) __syncthreads();
    }

#pragma unroll
    for (int mi = 0; mi < 4; ++mi)
#pragma unroll
        for (int ni = 0; ni < 4; ++ni) {
            int col = colbase + wc * 64 + ni * 16 + l16;
            float bqv = bq[col];
#pragma unroll
            for (int r = 0; r < 4; ++r) {
                int row = m0 + wr * 64 + mi * 16 + kg * 4 + r;
                q[(size_t)row * 256 + col] = f2b(acc[mi][ni][r] + bqv);
            }
        }
}

// ---------------------------------------------------------------------------
// proj_kv: k = bf16((xb@Wk + bk + enc)*scale); v = f16(xb@Wv + bv + enc).
// BK=32 dbuf, 48KB LDS, scalar epilogue (R4-proven).
// ---------------------------------------------------------------------------
__global__ __launch_bounds__(256, 2) void proj_kv(
    const u16* __restrict__ xb, const float* __restrict__ enc,
    const u16* __restrict__ WT,
    const float* __restrict__ bk, const float* __restrict__ bv,
    u16* __restrict__ k, u16* __restrict__ v)
{
    __shared__ u16 sA[2 * 4096];
    __shared__ u16 sB0[2 * 4096];
    __shared__ u16 sB1[2 * 4096];
    const int t = threadIdx.x;
    const int colbase = blockIdx.x * 128;
    const int m0 = blockIdx.y * 128;
    const int wave = t >> 6, lane = t & 63;
    const int wr = wave >> 1, wc = wave & 1;
    const int l16 = lane & 15, kg = lane >> 4;
    const int lrow = lane >> 2, slot = lane & 3;

    const u16* gA = xb + (size_t)m0 * C_;
    const u16* gB0 = WT + 65536 + (size_t)colbase * C_;
    const u16* gB1 = WT + 2 * 65536 + (size_t)colbase * C_;

    f32x4 acck[4][4], accv[4][4];
#pragma unroll
    for (int i = 0; i < 4; ++i)
#pragma unroll
        for (int j = 0; j < 4; ++j) {
            acck[i][j] = (f32x4){0.f, 0.f, 0.f, 0.f};
            accv[i][j] = (f32x4){0.f, 0.f, 0.f, 0.f};
        }

    STG(sA, gA, 0); STG(sB0, gB0, 0); STG(sB1, gB1, 0);
    __syncthreads();
#pragma unroll
    for (int it = 0; it < 8; ++it) {
        const int cur = it & 1;
        if (it < 7) { STG(sA + (cur ^ 1) * 4096, gA, (it + 1) * 32);
                      STG(sB0 + (cur ^ 1) * 4096, gB0, (it + 1) * 32);
                      STG(sB1 + (cur ^ 1) * 4096, gB1, (it + 1) * 32); }
        bf16x8 af[4], b0[4], b1[4];
#pragma unroll
        for (int mi = 0; mi < 4; ++mi)
            af[mi] = *(const bf16x8*)(sA + cur * 4096 + (wr * 64 + mi * 16 + l16) * 32 + kg * 8);
#pragma unroll
        for (int ni = 0; ni < 4; ++ni) {
            b0[ni] = *(const bf16x8*)(sB0 + cur * 4096 + (wc * 64 + ni * 16 + l16) * 32 + kg * 8);
            b1[ni] = *(const bf16x8*)(sB1 + cur * 4096 + (wc * 64 + ni * 16 + l16) * 32 + kg * 8);
        }
#pragma unroll
        for (int mi = 0; mi < 4; ++mi)
#pragma unroll
            for (int ni = 0; ni < 4; ++ni) {
                acck[mi][ni] = __builtin_amdgcn_mfma_f32_16x16x32_bf16(
                    af[mi], b0[ni], acck[mi][ni], 0, 0, 0);
                accv[mi][ni] = __builtin_amdgcn_mfma_f32_16x16x32_bf16(
                    af[mi], b1[ni], accv[mi][ni], 0, 0, 0);
            }
        if (it < 7) __syncthreads();
    }

    const float SCALE = 0.17677669529663687f;
#pragma unroll
    for (int mi = 0; mi < 4; ++mi)
#pragma unroll
        for (int ni = 0; ni < 4; ++ni) {
            int col = colbase + wc * 64 + ni * 16 + l16;
            float bkv = bk[col], bvv = bv[col];
#pragma unroll
            for (int r = 0; r < 4; ++r) {
                int row = m0 + wr * 64 + mi * 16 + kg * 4 + r;
                size_t off = (size_t)row * 256 + col;
                float e = enc[off];
                k[off] = f2b((acck[mi][ni][r] + bkv + e) * SCALE);
                v[off] = f2h(accv[mi][ni][r] + bvv + e);
            }
        }
}

// ---------------------------------------------------------------------------
// dwconv5x5: v (f16) -> lepe (bf16), packed f16 math, 4 output pixels/thread.
// ---------------------------------------------------------------------------
__global__ __launch_bounds__(256) void dwconv5x5(
    const u16* __restrict__ vh, const u16* __restrict__ cwh,
    const float* __restrict__ cb, u16* __restrict__ lepeb)
{
    size_t tid = (size_t)blockIdx.x * 256 + threadIdx.x;   // [0, 589824)
    int c8 = (int)(tid & 31);
    size_t rest = tid >> 5;
    int wi = (int)(rest % 24);
    size_t tmp = rest / 24;
    int h = (int)(tmp % S_);
    int b = (int)(tmp / S_);
    int w0 = wi * 4;
    int c0 = c8 * 8;

    hf8 z;
#pragma unroll
    for (int q = 0; q < 8; ++q) z[q] = (_Float16)0.f;
    hf8 acc[4] = { z, z, z, z };

#pragma unroll
    for (int dy = -2; dy <= 2; ++dy) {
        int hy = h + dy;
        if (hy < 0 || hy >= S_) continue;
        const u16* rowp = vh + (((size_t)b * S_ + hy) * S_) * C_ + c0;
        hf8 vr[8];
#pragma unroll
        for (int i = 0; i < 8; ++i) {
            int c = w0 - 2 + i;
            vr[i] = (c >= 0 && c < S_) ? *(const hf8*)(rowp + (size_t)c * C_) : z;
        }
#pragma unroll
        for (int dx = 0; dx < 5; ++dx) {
            hf8 ww = *(const hf8*)(cwh + (size_t)((dy + 2) * 5 + dx) * C_ + c0);
#pragma unroll
            for (int r = 0; r < 4; ++r) acc[r] += vr[dx + r] * ww;
        }
    }

    float4 cb0 = *(const float4*)(cb + c0);
    float4 cb1 = *(const float4*)(cb + c0 + 4);
    float cbv[8] = { cb0.x, cb0.y, cb0.z, cb0.w, cb1.x, cb1.y, cb1.z, cb1.w };
    size_t pix0 = ((size_t)b * S_ + h) * S_ + w0;
#pragma unroll
    for (int r = 0; r < 4; ++r) {
        u16 o[8];
#pragma unroll
        for (int q = 0; q < 8; ++q) o[q] = f2b((float)acc[r][q] + cbv[q]);
        *(int4*)(lepeb + (pix0 + r) * C_ + c0) = *(int4*)o;
    }
}

// ---------------------------------------------------------------------------
// axial<HM>: MFMA axial attention with LOG-softmax.
//  HM=0 (width):  V-in = v (f16), out = v1 (fp32, d_out), A f16 PV
//  HM=1 (height): V-in = v1 (fp32, hi/lo bf16 split), out = bf16(out2 + lepe)
//                 into the q-buffer (in place per-slice).
// ---------------------------------------------------------------------------
template<int HM>
__global__ __launch_bounds__(128, 3) void axial(
    const u16* __restrict__ qb, const u16* __restrict__ kb,
    const void* __restrict__ vin, void* __restrict__ vout,
    const u16* __restrict__ lep, int ofac, int pstride)
{
    __shared__ u16 sQ[96][56];
    __shared__ u16 sK[96][56];
    __shared__ u16 sVT[HM + 1][32][104];
    __shared__ u16 sAh[2][16][40];
    __shared__ u16 sAl[2][16][40];

    const int t = threadIdx.x;
    const int wave = t >> 6, lane = t & 63;
    const int l16 = lane & 15, kg = lane >> 4;

    const int n = blockIdx.x & 7;
    const int o = (blockIdx.x >> 3) % 96;
    const int b = blockIdx.x / (8 * 96);
    const size_t base = ((size_t)b * 9216 + (size_t)o * ofac) * C_ + n * D_;

    if (t < 96) {
        const u16* gq = qb + base + (size_t)t * pstride;
        const u16* gk = kb + base + (size_t)t * pstride;
#pragma unroll
        for (int c = 0; c < 4; ++c) {
            *(int4*)&sQ[t][c * 8] = *(const int4*)(gq + c * 8);
            *(int4*)&sK[t][c * 8] = *(const int4*)(gk + c * 8);
        }
    }
    if (HM == 0) {
        const u16* vb = (const u16*)vin;
#pragma unroll
        for (int p = 0; p < 3; ++p) {
            int j = p * 32 + (t >> 2);
            int dc = (t & 3) * 8;
            int4 raw = *(const int4*)(vb + base + (size_t)j * pstride + dc);
            const u16* e = (const u16*)&raw;
#pragma unroll
            for (int q = 0; q < 8; ++q) sVT[0][dc + q][j] = e[q];
        }
    } else {
        const float* v1 = (const float*)vin;
#pragma unroll
        for (int p = 0; p < 6; ++p) {
            int j = p * 16 + (t >> 3);
            int db = (t & 7) * 4;
            float4 f = *(const float4*)(v1 + base + (size_t)j * pstride + db);
            float fv[4] = { f.x, f.y, f.z, f.w };
#pragma unroll
            for (int q = 0; q < 4; ++q) {
                u16 hi = f2b(fv[q]);
                sVT[0][db + q][j] = hi;
                sVT[HM][db + q][j] = f2b(fv[q] - b2f(hi));
            }
        }
    }
    __syncthreads();

    bf16x8 kf[6];
#pragma unroll
    for (int f = 0; f < 6; ++f)
        kf[f] = *(const bf16x8*)&sK[f * 16 + l16][kg * 8];

    const f32x4 zero = {0.f, 0.f, 0.f, 0.f};

    for (int p = 0; p < 3; ++p) {
        const int g = wave * 3 + p;
        bf16x8 qf = *(const bf16x8*)&sQ[g * 16 + l16][kg * 8];
        f32x4 s[6];
#pragma unroll
        for (int f = 0; f < 6; ++f)
            s[f] = __builtin_amdgcn_mfma_f32_16x16x32_bf16(kf[f], qf, zero, 0, 0, 0);

        float m = s[0][0];
#pragma unroll
        for (int f = 0; f < 6; ++f)
#pragma unroll
            for (int r = 0; r < 4; ++r) m = fmaxf(m, s[f][r]);
        m = fmaxf(m, __shfl_xor(m, 16));
        m = fmaxf(m, __shfl_xor(m, 32));
        float l = 0.f;
#pragma unroll
        for (int f = 0; f < 6; ++f)
#pragma unroll
            for (int r = 0; r < 4; ++r) l += __expf(s[f][r] - m);
        l += __shfl_xor(l, 16);
        l += __shfl_xor(l, 32);
        float lse = m + __logf(l);

        u16 ah[6][4], al[6][4];
#pragma unroll
        for (int f = 0; f < 6; ++f)
#pragma unroll
            for (int r = 0; r < 4; ++r) {
                float a = s[f][r] - lse;
                ah[f][r] = (HM == 0) ? f2h(a) : f2b(a);
                if (HM) al[f][r] = f2b(a - b2f(ah[f][r]));
            }

        f32x4 pacc[2] = { zero, zero };
#pragma unroll
        for (int c = 0; c < 3; ++c) {
#pragma unroll
            for (int fi = 0; fi < 2; ++fi)
#pragma unroll
                for (int r = 0; r < 4; ++r) {
                    int col = fi * 16 + kg * 4 + r;
                    sAh[wave][l16][col] = ah[2 * c + fi][r];
                    if (HM) sAl[wave][l16][col] = al[2 * c + fi][r];
                }
            if (HM == 0) {
                hf8 ahf = *(const hf8*)&sAh[wave][l16][kg * 8];
#pragma unroll
                for (int nf = 0; nf < 2; ++nf) {
                    hf8 vt = *(const hf8*)&sVT[0][nf * 16 + l16][c * 32 + kg * 8];
                    pacc[nf] = __builtin_amdgcn_mfma_f32_16x16x32_f16(ahf, vt, pacc[nf], 0, 0, 0);
                }
            } else {
                bf16x8 ahf = *(const bf16x8*)&sAh[wave][l16][kg * 8];
                bf16x8 alf = *(const bf16x8*)&sAl[wave][l16][kg * 8];
#pragma unroll
                for (int nf = 0; nf < 2; ++nf) {
                    bf16x8 vt = *(const bf16x8*)&sVT[0][nf * 16 + l16][c * 32 + kg * 8];
                    bf16x8 vtl = *(const bf16x8*)&sVT[HM][nf * 16 + l16][c * 32 + kg * 8];
                    pacc[nf] = __builtin_amdgcn_mfma_f32_16x16x32_bf16(ahf, vt, pacc[nf], 0, 0, 0);
                    pacc[nf] = __builtin_amdgcn_mfma_f32_16x16x32_bf16(ahf, vtl, pacc[nf], 0, 0, 0);
                    pacc[nf] = __builtin_amdgcn_mfma_f32_16x16x32_bf16(alf, vt, pacc[nf], 0, 0, 0);
                }
            }
        }

#pragma unroll
        for (int nf = 0; nf < 2; ++nf)
#pragma unroll
            for (int r = 0; r < 4; ++r) {
                int qi = g * 16 + kg * 4 + r;
                size_t off = base + (size_t)qi * pstride + nf * 16 + l16;
                if (HM == 0) {
                    ((float*)vout)[off] = pacc[nf][r];
                } else {
                    float lv = b2f(lep[off]);             // fuse +lepe here
                    ((u16*)vout)[off] = f2b(pacc[nf][r] + lv);
                }
            }
    }
}

// ---------------------------------------------------------------------------
// out_gemm: out = o2sum @ Wo + bo (o2sum = attn+lepe, pre-added in axial<1>).
// Identical structure to proj_q; fp32 epilogue.
// ---------------------------------------------------------------------------
__global__ __launch_bounds__(256, 3) void out_gemm(
    const u16* __restrict__ o2b, const u16* __restrict__ WoT,
    const float* __restrict__ bo, float* __restrict__ out)
{
    __shared__ u16 sA[2 * 4096];
    __shared__ u16 sB[2 * 4096];
    const int t = threadIdx.x;
    const int colbase = blockIdx.x * 128;
    const int m0 = blockIdx.y * 128;
    const int wave = t >> 6, lane = t & 63;
    const int wr = wave >> 1, wc = wave & 1;
    const int l16 = lane & 15, kg = lane >> 4;
    const int lrow = lane >> 2, slot = lane & 3;

    const u16* gA = o2b + (size_t)m0 * C_;
    const u16* gB = WoT + (size_t)colbase * C_;

    f32x4 acc[4][4];
#pragma unroll
    for (int i = 0; i < 4; ++i)
#pragma unroll
        for (int j = 0; j < 4; ++j) acc[i][j] = (f32x4){0.f, 0.f, 0.f, 0.f};

    STG(sA, gA, 0); STG(sB, gB, 0);
    __syncthreads();
#pragma unroll
    for (int it = 0; it < 8; ++it) {
        const int cur = it & 1;
        if (it < 7) { STG(sA + (cur ^ 1) * 4096, gA, (it + 1) * 32);
                      STG(sB + (cur ^ 1) * 4096, gB, (it + 1) * 32); }
        bf16x8 af[4], bf[4];
#pragma unroll
        for (int mi = 0; mi < 4; ++mi)
            af[mi] = *(const bf16x8*)(sA + cur * 4096 + (wr * 64 + mi * 16 + l16) * 32 + kg * 8);
#pragma unroll
        for (int ni = 0; ni < 4; ++ni)
            bf[ni] = *(const bf16x8*)(sB + cur * 4096 + (wc * 64 + ni * 16 + l16) * 32 + kg * 8);
#pragma unroll
        for (int mi = 0; mi < 4; ++mi)
#pragma unroll
            for (int ni = 0; ni < 4; ++ni)
                acc[mi][ni] = __builtin_amdgcn_mfma_f32_16x16x32_bf16(
                    af[mi], bf[ni], acc[mi][ni], 0, 0, 0);
        if (it < 7) __syncthreads();
    }

#pragma unroll
    for (int mi = 0; mi < 4; ++mi)
#pragma unroll
        for (int ni = 0; ni < 4; ++ni) {
            int col = colbase + wc * 64 + ni * 16 + l16;
            float bv_ = bo[col];
#pragma unroll
            for (int r = 0; r < 4; ++r) {
                int row = m0 + wr * 64 + mi * 16 + kg * 4 + r;
                out[(size_t)row * 256 + col] = acc[mi][ni][r] + bv_;
            }
        }
}

extern "C" void kernel_launch(void* const* d_in, const int* in_sizes, int n_in,
                              void* d_out, int out_size, void* d_ws, size_t ws_size,
                              hipStream_t stream)
{
    const float* x   = (const float*)d_in[0];
    const float* enc = (const float*)d_in[1];
    const float* Wq  = (const float*)d_in[2];
    const float* bq  = (const float*)d_in[3];
    const float* Wk  = (const float*)d_in[4];
    const float* bk  = (const float*)d_in[5];
    const float* Wv  = (const float*)d_in[6];
    const float* bv  = (const float*)d_in[7];
    const float* cw  = (const float*)d_in[8];
    const float* cb  = (const float*)d_in[9];
    const float* Wo  = (const float*)d_in[10];
    const float* bo  = (const float*)d_in[11];

    u16* qbuf = (u16*)d_ws;            // SZ bf16 (later out2+lepe)
    u16* kbuf = qbuf + SZ;             // SZ bf16
    u16* vbuf = kbuf + SZ;             // SZ f16
    u16* WT   = vbuf + SZ;             // 4 * 65536 bf16
    u16* cwh  = WT + 4 * 65536;        // 6400 f16
    u16* xb   = cwh + 6400;            // SZ bf16
    u16* lep  = xb + SZ;               // SZ bf16
    float* v1 = (float*)d_out;         // width-stage PV output lives in d_out

    prep_x<<<9216, 256, 0, stream>>>(x, xb);
    prep_w<<<1024, 256, 0, stream>>>(Wq, Wk, Wv, Wo, WT);
    prep_cw<<<25, 256, 0, stream>>>(cw, cwh);
    proj_q<<<dim3(2, 576), 256, 0, stream>>>(xb, WT, bq, qbuf);
    proj_kv<<<dim3(2, 576), 256, 0, stream>>>(xb, enc, WT, bk, bv, kbuf, vbuf);
    dwconv5x5<<<2304, 256, 0, stream>>>(vbuf, cwh, cb, lep);
    // width: o = image row, positions = w (stride C_)
    axial<0><<<B_ * 96 * NH_, 128, 0, stream>>>(qbuf, kbuf, vbuf, v1, nullptr, 96, 256);
    // height: o = image col, positions = h (stride 96*C_); out2+lepe -> qbuf
    axial<1><<<B_ * 96 * NH_, 128, 0, stream>>>(qbuf, kbuf, v1, qbuf, lep, 1, 96 * 256);
    out_gemm<<<dim3(2, 576), 256, 0, stream>>>(qbuf, WT + 3 * 65536, bo, (float*)d_out);
}